// Round 18
// baseline (548.749 us; speedup 1.0000x reference)
//
#include <hip/hip_runtime.h>
#include <hip/hip_bf16.h>

#define SLOW 32
#define MSG 16
#define TSTEPS 4
#define BATCH 8
#define NI0 256
#define NO0 128
#define NI1 128
#define NO1 64

typedef __bf16 bf16x8 __attribute__((ext_vector_type(8)));
typedef float f32x4 __attribute__((ext_vector_type(4)));

__device__ __forceinline__ float rcpf(float x) { return __builtin_amdgcn_rcpf(x); }
__device__ __forceinline__ float sigf(float x) { return rcpf(1.f + __expf(-x)); }
__device__ __forceinline__ float tanh_apx(float x) {
    float xc = fminf(fmaxf(x, -15.f), 15.f);
    float e = __expf(-2.f * xc);
    return (1.f - e) * rcpf(1.f + e);
}
__device__ __forceinline__ unsigned short f2bf(float x) {
    __bf16 h = (__bf16)x;
    return __builtin_bit_cast(unsigned short, h);
}
__device__ __forceinline__ float bf2f(unsigned short u) {
    __bf16 h = __builtin_bit_cast(__bf16, u);
    return (float)h;
}
__device__ __forceinline__ float sum16(float v) {
    v += __shfl_xor(v, 1); v += __shfl_xor(v, 2);
    v += __shfl_xor(v, 4); v += __shfl_xor(v, 8);
    return v;
}

// ---------------------------------------------------------------------------
// k_prep: pack B-fragments (bf16) for Wh (8 nt), Wf, Wb, Wi-fwd (8 nt, K pad)
// ---------------------------------------------------------------------------
__global__ void k_prep(const float* __restrict__ Wh, const float* __restrict__ Wf,
                       const float* __restrict__ Wb, const float* __restrict__ Wi,
                       unsigned short* __restrict__ WhBp,
                       unsigned short* __restrict__ WfBp,
                       unsigned short* __restrict__ WbBp,
                       unsigned short* __restrict__ WiFp) {
    int i = blockIdx.x * 256 + threadIdx.x;
    if (i < 4096) {
        int e = i & 7, l = (i >> 3) & 63, nt = i >> 9;
        int k = (l >> 4) * 8 + e, col = nt * 16 + (l & 15);
        WhBp[i] = f2bf(Wh[k * 128 + col]);
    } else if (i < 4608) {
        int j = i - 4096;
        int e = j & 7, l = j >> 3;
        int k = (l >> 4) * 8 + e;
        WfBp[j] = f2bf(Wf[k * 16 + (l & 15)]);
    } else if (i < 5120) {
        int j = i - 4608;
        int e = j & 7, l = j >> 3;
        int k = (l >> 4) * 8 + e;
        WbBp[j] = f2bf(Wb[k * 16 + (l & 15)]);
    } else if (i < 9216) {
        int j = i - 5120;
        int e = j & 7, l = (j >> 3) & 63, nt = j >> 9;
        int k = (l >> 4) * 8 + e, col = nt * 16 + (l & 15);
        WiFp[j] = (k < 16) ? f2bf(Wi[k * 128 + col]) : (unsigned short)0;
    }
}

// ---------------------------------------------------------------------------
// Layer 0 (+ overlapped l1-merge & softmax for the previous step):
//   blocks [0,2048)      : LSTM (b,no,q), 4 waves, 128 cells
//   blocks [2048,2304)   : hm1 merge (t>0)
//   blocks [2304,2432)   : cm1 merge (t>0)
//   blocks [2432,2440)   : softmax/error for step t-1 (t>0)
// ---------------------------------------------------------------------------
__global__ __launch_bounds__(256, 6) void k_l0(
    const float* __restrict__ inp, const float* __restrict__ Wi,
    const unsigned short* __restrict__ WhBp, const float* __restrict__ b_lstm,
    const unsigned short* __restrict__ WfBp, const float* __restrict__ bf_,
    const float* __restrict__ ln_fs, const float* __restrict__ ln_fb,
    unsigned short* __restrict__ h0bf, float* __restrict__ c0g,
    const unsigned short* __restrict__ hm0, const float* __restrict__ cm0,
    const unsigned int* __restrict__ h1bf, const float* __restrict__ c1g,
    unsigned short* __restrict__ hm1, float* __restrict__ cm1,
    const float* __restrict__ outsum_part, const int* __restrict__ labels,
    float* __restrict__ dout, float* __restrict__ gradP, float* __restrict__ ohP,
    const float* __restrict__ nb1, float* __restrict__ nf_part, int t) {
    int tid = threadIdx.x;
    if (blockIdx.x >= 2048) {
        int mb = blockIdx.x - 2048;
        if (mb < 256) {   // hm1: 65536 u32 tasks
            int idx = mb * 256 + tid;
            int u = idx & 7, cell = (idx >> 3) & 127, no = idx >> 10;
            size_t base = ((size_t)no * 128 + cell) * 16 + u;
            const size_t strd = (size_t)NO1 * 128 * 16;
            float s0 = 0.f, s1 = 0.f;
#pragma unroll
            for (int b = 0; b < 8; b++) {
                unsigned int v = h1bf[base + b * strd];
                s0 += bf2f((unsigned short)(v & 0xffff));
                s1 += bf2f((unsigned short)(v >> 16));
            }
            ((unsigned int*)hm1)[((size_t)no * 128 + cell) * 8 + u] =
                (unsigned int)f2bf(s0 * 0.125f) | ((unsigned int)f2bf(s1 * 0.125f) << 16);
            return;
        }
        if (mb < 384) {   // cm1: 32768 float4 tasks
            int idx = (mb - 256) * 256 + tid;
            int s4 = idx & 3, cell = (idx >> 2) & 127, no = idx >> 9;
            const float4* C = (const float4*)c1g;
            size_t base = ((size_t)no * 128 + cell) * 8 + s4;
            const size_t strd = (size_t)NO1 * 128 * 8;
            float4 a = {0.f, 0.f, 0.f, 0.f};
#pragma unroll
            for (int b = 0; b < 8; b++) {
                float4 v = C[base + b * strd];
                a.x += v.x; a.y += v.y; a.z += v.z; a.w += v.w;
            }
            a.x *= 0.125f; a.y *= 0.125f; a.z *= 0.125f; a.w *= 0.125f;
            ((float4*)cm1)[((size_t)no * 128 + cell) * 4 + s4] = a;
            return;
        }
        {   // softmax for step t-1
            int b = mb - 384;
            int no = tid;
            if (no < 64) {
                float v = (outsum_part[((size_t)b * NO1 + no) * 2] +
                           outsum_part[((size_t)b * NO1 + no) * 2 + 1]) * (1.f / 128.f);
                float mx = v;
#pragma unroll
                for (int d = 1; d < 64; d <<= 1) mx = fmaxf(mx, __shfl_xor(mx, d));
                float e = __expf(v - mx);
                float sum = e;
#pragma unroll
                for (int d = 1; d < 64; d <<= 1) sum += __shfl_xor(sum, d);
                int lbl = labels[(t - 1) * BATCH + b];
                float oh = (no == lbl) ? 1.f : 0.f;
                gradP[b * NO1 + no] = e / sum - oh;
                ohP[b * NO1 + no] = oh;
                dout[((size_t)(t - 1) * BATCH + b) * NO1 + no] = v;
            }
            return;
        }
    }

    int q = blockIdx.x & 1;
    int no = (blockIdx.x >> 1) & 127;
    int b = blockIdx.x >> 8;
    int w = __builtin_amdgcn_readfirstlane(tid >> 6);
    int l = tid & 63, lo = l & 15, hg = l >> 4;
    const bool wb = (t < TSTEPS - 1);

    __shared__ unsigned short Hbf[128 * 40];
    __shared__ unsigned short BW[4096];
    __shared__ unsigned short BFr[512];
    __shared__ float gsh[128];
    __shared__ float mi_l[128];
    __shared__ float wi0[128];
    __shared__ float redn[4][16];

    {
        unsigned int* d = (unsigned int*)BW;
        const unsigned int* s = (const unsigned int*)WhBp;
#pragma unroll
        for (int i = tid; i < 2048; i += 256) d[i] = s[i];
        ((unsigned int*)BFr)[tid] = ((const unsigned int*)WfBp)[tid];
    }
    if (tid < 128) {
        float acc = b_lstm[tid];
        if (t > 0) {
            const float* nbr = nb1 + ((size_t)b * NO0 + no) * MSG;
#pragma unroll
            for (int m = 0; m < MSG; m++) acc += nbr[m] * Wi[(MSG + m) * 128 + tid];
        }
        gsh[tid] = acc;
        wi0[tid] = Wi[tid];
        mi_l[tid] = inp[((size_t)t * BATCH + b) * NI0 + q * 128 + tid];
    }
    {
        int lc = tid >> 1, half = tid & 1;
        unsigned int* hl = (unsigned int*)Hbf;
        if (t > 0) {
            if (half == 0) {
                const unsigned int* hsrc = (const unsigned int*)hm0 +
                    ((size_t)no * 256 + q * 128 + lc) * 8;
#pragma unroll
                for (int j = 0; j < 8; j++) hl[lc * 20 + j] = hsrc[j];
            } else {
                const unsigned int* hsrc = (const unsigned int*)h0bf +
                    ((size_t)(b * NO0 + no) * 256 + q * 128 + lc) * 16 + 8;
#pragma unroll
                for (int j = 0; j < 8; j++) hl[lc * 20 + 8 + j] = hsrc[j];
            }
        } else {
#pragma unroll
            for (int j = 0; j < 8; j++) hl[lc * 20 + half * 8 + j] = 0u;
        }
    }
    size_t cbase = (size_t)(b * NO0 + no) * 256 * 32;
    float cst[2][4][2];
    if (t > 0) {
#pragma unroll
        for (int mi_ = 0; mi_ < 2; mi_++)
#pragma unroll
            for (int r = 0; r < 4; r++) {
                int gc = q * 128 + (w * 2 + mi_) * 16 + hg * 4 + r;
                cst[mi_][r][0] = cm0[((size_t)no * 256 + gc) * 16 + lo];
                cst[mi_][r][1] = c0g[cbase + (size_t)gc * 32 + lo + 16];
            }
    } else {
#pragma unroll
        for (int mi_ = 0; mi_ < 2; mi_++)
#pragma unroll
            for (int r = 0; r < 4; r++) { cst[mi_][r][0] = 0.f; cst[mi_][r][1] = 0.f; }
    }
    __syncthreads();

    float g8[8], w8[8];
#pragma unroll
    for (int nt = 0; nt < 8; nt++) { g8[nt] = gsh[lo + 16 * nt]; w8[nt] = wi0[lo + 16 * nt]; }
    f32x4 miv[2];
#pragma unroll
    for (int mi_ = 0; mi_ < 2; mi_++)
#pragma unroll
        for (int r = 0; r < 4; r++)
            miv[mi_][r] = mi_l[(w * 2 + mi_) * 16 + hg * 4 + r];

#pragma unroll
    for (int micro = 0; micro < 2; micro++) {
#pragma unroll
        for (int mi_ = 0; mi_ < 2; mi_++) {
            int lt = w * 2 + mi_;
            bf16x8 A = *(const bf16x8*)&Hbf[(lt * 16 + lo) * 40 + hg * 8];
            f32x4 acc[4];
#pragma unroll
            for (int g = 0; g < 4; g++) {
                int nt = 2 * g;
                bf16x8 B = *(const bf16x8*)&BW[(nt * 64 + l) * 8];
                f32x4 ci = g8[nt] + miv[mi_] * w8[nt];
                acc[g] = __builtin_amdgcn_mfma_f32_16x16x32_bf16(A, B, ci, 0, 0, 0);
            }
#pragma unroll
            for (int r = 0; r < 4; r++) {
                int lrow = lt * 16 + hg * 4 + r;
                float cn = sigf(acc[1][r]) * cst[mi_][r][0] + sigf(acc[0][r]) * tanh_apx(acc[2][r]);
                cst[mi_][r][0] = cn;
                float hv = sigf(acc[3][r]) * tanh_apx(cn);
                Hbf[lrow * 40 + lo] = f2bf(hv);
                if (micro == 1 && wb)
                    c0g[cbase + (size_t)(q * 128 + lrow) * 32 + lo] = cn;
            }
#pragma unroll
            for (int g = 0; g < 4; g++) {
                int nt = 2 * g + 1;
                bf16x8 B = *(const bf16x8*)&BW[(nt * 64 + l) * 8];
                f32x4 ci = g8[nt] + miv[mi_] * w8[nt];
                acc[g] = __builtin_amdgcn_mfma_f32_16x16x32_bf16(A, B, ci, 0, 0, 0);
            }
#pragma unroll
            for (int r = 0; r < 4; r++) {
                int lrow = lt * 16 + hg * 4 + r;
                float cn = sigf(acc[1][r]) * cst[mi_][r][1] + sigf(acc[0][r]) * tanh_apx(acc[2][r]);
                cst[mi_][r][1] = cn;
                float hv = sigf(acc[3][r]) * tanh_apx(cn);
                Hbf[lrow * 40 + lo + 16] = f2bf(hv);
                if (micro == 1 && wb)
                    c0g[cbase + (size_t)(q * 128 + lrow) * 32 + lo + 16] = cn;
            }
        }
    }

    // epilogue: fm = LN(h @ Wf + bf); raw partial sums
    bf16x8 Ff = *(const bf16x8*)&BFr[l * 8];
    float lnfs = ln_fs[lo], lnfb = ln_fb[lo];
    float bfv = bf_[lo];
    f32x4 cif = {bfv, bfv, bfv, bfv};
    float nfp = 0.f;
#pragma unroll
    for (int mi_ = 0; mi_ < 2; mi_++) {
        int lt = w * 2 + mi_;
        bf16x8 A = *(const bf16x8*)&Hbf[(lt * 16 + lo) * 40 + hg * 8];
        f32x4 f = __builtin_amdgcn_mfma_f32_16x16x32_bf16(A, Ff, cif, 0, 0, 0);
#pragma unroll
        for (int r = 0; r < 4; r++) {
            float x = f[r];
            float mean = sum16(x) * 0.0625f;
            float d = x - mean;
            float rs = rsqrtf(sum16(d * d) * 0.0625f + 1e-6f);
            nfp += d * rs * lnfs + lnfb;
        }
    }
    nfp += __shfl_xor(nfp, 16);
    nfp += __shfl_xor(nfp, 32);
    if (l < 16) redn[w][l] = nfp;
    __syncthreads();
    if (tid < 16)
        nf_part[(((size_t)b * NO0 + no) * 2 + q) * 16 + tid] =
            redn[0][tid] + redn[1][tid] + redn[2][tid] + redn[3][tid];

    if (wb) {
        int lc = tid >> 1, part = tid & 1;
        unsigned int* hdst =
            (unsigned int*)h0bf +
            ((size_t)(b * NO0 + no) * 256 + q * 128 + lc) * 16 + part * 8;
        const unsigned int* hl = (const unsigned int*)Hbf;
#pragma unroll
        for (int j = 0; j < 8; j++) hdst[j] = hl[lc * 20 + part * 8 + j];
    }
}

// ---------------------------------------------------------------------------
// Layer 1: blocks [0,1024) = LSTM; blocks [1024,2560) = layer-0 merge.
// ---------------------------------------------------------------------------
__global__ __launch_bounds__(256) void k_l1(
    const float* __restrict__ Wi, const unsigned short* __restrict__ WhBp,
    const float* __restrict__ b_lstm,
    const unsigned short* __restrict__ WfBp, const float* __restrict__ bf_,
    const float* __restrict__ ln_fs, const float* __restrict__ ln_fb,
    const unsigned short* __restrict__ WbBp, const float* __restrict__ bwb,
    const float* __restrict__ ln_bs, const float* __restrict__ ln_bb,
    const unsigned short* __restrict__ WiFp,
    unsigned short* __restrict__ h1bf, float* __restrict__ c1g,
    const unsigned short* __restrict__ hm1, const float* __restrict__ cm1,
    const unsigned short* __restrict__ h0bf, const float* __restrict__ c0g,
    unsigned short* __restrict__ hm0, float* __restrict__ cm0,
    const float* __restrict__ nf_part, const float* __restrict__ gradP,
    const float* __restrict__ ohP,
    float* __restrict__ bm_g, float* __restrict__ outsum_part, int t) {
    int tid = threadIdx.x;
    if (blockIdx.x >= 1024) {
        int mb = blockIdx.x - 1024;
        if (mb < 1024) {  // hm0
            int idx = mb * 256 + tid;
            int u = idx & 7, cell = (idx >> 3) & 255, no = idx >> 11;
            size_t base = ((size_t)no * 256 + cell) * 16 + u;
            const size_t strd = (size_t)NO0 * 256 * 16;
            const unsigned int* H = (const unsigned int*)h0bf;
            float s0 = 0.f, s1 = 0.f;
#pragma unroll
            for (int b = 0; b < 8; b++) {
                unsigned int v = H[base + b * strd];
                s0 += bf2f((unsigned short)(v & 0xffff));
                s1 += bf2f((unsigned short)(v >> 16));
            }
            ((unsigned int*)hm0)[((size_t)no * 256 + cell) * 8 + u] =
                (unsigned int)f2bf(s0 * 0.125f) | ((unsigned int)f2bf(s1 * 0.125f) << 16);
        } else {          // cm0
            int idx = (mb - 1024) * 256 + tid;
            int s4 = idx & 3, cell = (idx >> 2) & 255, no = idx >> 10;
            const float4* C = (const float4*)c0g;
            size_t base = ((size_t)no * 256 + cell) * 8 + s4;
            const size_t strd = (size_t)NO0 * 256 * 8;
            float4 a = {0.f, 0.f, 0.f, 0.f};
#pragma unroll
            for (int b = 0; b < 8; b++) {
                float4 v = C[base + b * strd];
                a.x += v.x; a.y += v.y; a.z += v.z; a.w += v.w;
            }
            a.x *= 0.125f; a.y *= 0.125f; a.z *= 0.125f; a.w *= 0.125f;
            ((float4*)cm0)[((size_t)no * 256 + cell) * 4 + s4] = a;
        }
        return;
    }

    int q = blockIdx.x & 1;
    int no = (blockIdx.x >> 1) & 63;
    int b = blockIdx.x >> 7;
    int w = __builtin_amdgcn_readfirstlane(tid >> 6);
    int l = tid & 63, lo = l & 15, hg = l >> 4;
    const bool wb = (t < TSTEPS - 1);

    __shared__ unsigned short Hbf[64 * 40];
    __shared__ unsigned short BW[4096];
    __shared__ unsigned short WiF[4096];
    __shared__ unsigned short BFr[512];
    __shared__ unsigned short BBr[512];
    __shared__ float gsh[128];
    __shared__ float red[4];

    {
        unsigned int* d = (unsigned int*)BW;
        const unsigned int* s = (const unsigned int*)WhBp;
        unsigned int* d2 = (unsigned int*)WiF;
        const unsigned int* s2 = (const unsigned int*)WiFp;
#pragma unroll
        for (int i = tid; i < 2048; i += 256) { d[i] = s[i]; d2[i] = s2[i]; }
        ((unsigned int*)BFr)[tid] = ((const unsigned int*)WfBp)[tid];
        ((unsigned int*)BBr)[tid] = ((const unsigned int*)WbBp)[tid];
    }
    if (tid < 128) {
        float acc = b_lstm[tid];
        if (t > 0) {
            float g = gradP[b * NO1 + no], oh = ohP[b * NO1 + no];
            acc += g * Wi[MSG * 128 + tid] + oh * Wi[(MSG + 1) * 128 + tid];
        }
        gsh[tid] = acc;
    }
    {
        int lc = tid >> 2, part = tid & 3;
        unsigned int* hl = (unsigned int*)Hbf;
        if (t > 0) {
            if (part < 2) {
                const unsigned int* hsrc = (const unsigned int*)hm1 +
                    ((size_t)no * 128 + q * 64 + lc) * 8 + part * 4;
#pragma unroll
                for (int j = 0; j < 4; j++) hl[lc * 20 + part * 4 + j] = hsrc[j];
            } else {
                const unsigned int* hsrc = (const unsigned int*)h1bf +
                    ((size_t)(b * NO1 + no) * 128 + q * 64 + lc) * 16 + part * 4;
#pragma unroll
                for (int j = 0; j < 4; j++) hl[lc * 20 + part * 4 + j] = hsrc[j];
            }
        } else {
#pragma unroll
            for (int j = 0; j < 4; j++) hl[lc * 20 + part * 4 + j] = 0u;
        }
    }
    size_t cbase = (size_t)(b * NO1 + no) * 128 * 32;
    float cst[4][2];
    if (t > 0) {
#pragma unroll
        for (int r = 0; r < 4; r++) {
            int gc = q * 64 + w * 16 + hg * 4 + r;
            cst[r][0] = cm1[((size_t)no * 128 + gc) * 16 + lo];
            cst[r][1] = c1g[cbase + (size_t)gc * 32 + lo + 16];
        }
    } else {
#pragma unroll
        for (int r = 0; r < 4; r++) { cst[r][0] = 0.f; cst[r][1] = 0.f; }
    }
    bf16x8 Anf;
#pragma unroll
    for (int e = 0; e < 8; e++) Anf[e] = (__bf16)0.f;
    if (hg < 2) {
        const float* p = nf_part +
            ((size_t)b * 128 + q * 64 + w * 16 + lo) * 32 + hg * 8;
#pragma unroll
        for (int e = 0; e < 8; e++)
            Anf[e] = (__bf16)((p[e] + p[e + 16]) * (1.f / 256.f));
    }
    __syncthreads();

    f32x4 xf4[8];
    {
        f32x4 zz = {0.f, 0.f, 0.f, 0.f};
#pragma unroll
        for (int nt = 0; nt < 8; nt++) {
            bf16x8 B = *(const bf16x8*)&WiF[(nt * 64 + l) * 8];
            xf4[nt] = __builtin_amdgcn_mfma_f32_16x16x32_bf16(Anf, B, zz, 0, 0, 0);
        }
    }
    float g8[8];
#pragma unroll
    for (int nt = 0; nt < 8; nt++) g8[nt] = gsh[lo + 16 * nt];

#pragma unroll
    for (int micro = 0; micro < 2; micro++) {
        bf16x8 A = *(const bf16x8*)&Hbf[(w * 16 + lo) * 40 + hg * 8];
        f32x4 acc[4];
#pragma unroll
        for (int g = 0; g < 4; g++) {
            int nt = 2 * g;
            bf16x8 B = *(const bf16x8*)&BW[(nt * 64 + l) * 8];
            f32x4 ci = xf4[nt] + g8[nt];
            acc[g] = __builtin_amdgcn_mfma_f32_16x16x32_bf16(A, B, ci, 0, 0, 0);
        }
#pragma unroll
        for (int r = 0; r < 4; r++) {
            float cn = sigf(acc[1][r]) * cst[r][0] + sigf(acc[0][r]) * tanh_apx(acc[2][r]);
            cst[r][0] = cn;
            float hv = sigf(acc[3][r]) * tanh_apx(cn);
            Hbf[(w * 16 + hg * 4 + r) * 40 + lo] = f2bf(hv);
            if (micro == 1 && wb)
                c1g[cbase + (size_t)(q * 64 + w * 16 + hg * 4 + r) * 32 + lo] = cn;
        }
#pragma unroll
        for (int g = 0; g < 4; g++) {
            int nt = 2 * g + 1;
            bf16x8 B = *(const bf16x8*)&BW[(nt * 64 + l) * 8];
            f32x4 ci = xf4[nt] + g8[nt];
            acc[g] = __builtin_amdgcn_mfma_f32_16x16x32_bf16(A, B, ci, 0, 0, 0);
        }
#pragma unroll
        for (int r = 0; r < 4; r++) {
            float cn = sigf(acc[1][r]) * cst[r][1] + sigf(acc[0][r]) * tanh_apx(acc[2][r]);
            cst[r][1] = cn;
            float hv = sigf(acc[3][r]) * tanh_apx(cn);
            Hbf[(w * 16 + hg * 4 + r) * 40 + lo + 16] = f2bf(hv);
            if (micro == 1 && wb)
                c1g[cbase + (size_t)(q * 64 + w * 16 + hg * 4 + r) * 32 + lo + 16] = cn;
        }
    }

    bf16x8 Ff = *(const bf16x8*)&BFr[l * 8];
    float lnfs = ln_fs[lo], lnfb = ln_fb[lo];
    float bfv = bf_[lo];
    f32x4 cif = {bfv, bfv, bfv, bfv};
    float op = 0.f;
    {
        bf16x8 A = *(const bf16x8*)&Hbf[(w * 16 + lo) * 40 + hg * 8];
        f32x4 f = __builtin_amdgcn_mfma_f32_16x16x32_bf16(A, Ff, cif, 0, 0, 0);
#pragma unroll
        for (int r = 0; r < 4; r++) {
            float x = f[r];
            float mean = sum16(x) * 0.0625f;
            float d = x - mean;
            float rs = rsqrtf(sum16(d * d) * 0.0625f + 1e-6f);
            op += d * rs * lnfs + lnfb;
        }
        if (wb) {
            bf16x8 Bb = *(const bf16x8*)&BBr[l * 8];
            float lnbs = ln_bs[lo], lnbb = ln_bb[lo];
            float bwv = bwb[lo];
            f32x4 cib = {bwv, bwv, bwv, bwv};
            f32x4 g = __builtin_amdgcn_mfma_f32_16x16x32_bf16(A, Bb, cib, 0, 0, 0);
#pragma unroll
            for (int r = 0; r < 4; r++) {
                int gc = q * 64 + w * 16 + hg * 4 + r;
                float x = g[r];
                float mean = sum16(x) * 0.0625f;
                float d = x - mean;
                float rs = rsqrtf(sum16(d * d) * 0.0625f + 1e-6f);
                bm_g[(((size_t)b * NO1 + no) * MSG + lo) * NI1 + gc] = d * rs * lnbs + lnbb;
            }
        }
    }
    op += __shfl_xor(op, 16);
    op += __shfl_xor(op, 32);
    if (l == 0) red[w] = op;
    __syncthreads();
    if (tid == 0)
        outsum_part[((size_t)b * NO1 + no) * 2 + q] = red[0] + red[1] + red[2] + red[3];

    if (wb) {
        int lc = tid >> 2, part = tid & 3;
        unsigned int* hdst =
            (unsigned int*)h1bf +
            ((size_t)(b * NO1 + no) * 128 + q * 64 + lc) * 16 + part * 4;
        const unsigned int* hl = (const unsigned int*)Hbf;
#pragma unroll
        for (int j = 0; j < 4; j++) hdst[j] = hl[lc * 20 + part * 4 + j];
    }
}

// ---------------------------------------------------------------------------
// k_nb (t < TSTEPS-1): nb1[b][ni][m] = mean over no1 of bm_g
// ---------------------------------------------------------------------------
__global__ __launch_bounds__(256) void k_nb(const float* __restrict__ bm_g,
                                            float* __restrict__ nb1) {
    int g = blockIdx.x * 256 + threadIdx.x;  // < 16384
    int ni = g & 127;
    int m = (g >> 7) & 15;
    int b = g >> 11;
    float a = 0.f;
#pragma unroll 8
    for (int no = 0; no < NO1; no++)
        a += bm_g[(((size_t)b * NO1 + no) * MSG + m) * NI1 + ni];
    nb1[((size_t)b * NI1 + ni) * MSG + m] = a * (1.f / NO1);
}

// ---------------------------------------------------------------------------
// k_fin: final-step dout
// ---------------------------------------------------------------------------
__global__ void k_fin(const float* __restrict__ outsum_part,
                      float* __restrict__ dout) {
    int b = blockIdx.x;
    int no = threadIdx.x;
    float v = (outsum_part[((size_t)b * NO1 + no) * 2] +
               outsum_part[((size_t)b * NO1 + no) * 2 + 1]) * (1.f / 128.f);
    dout[((size_t)(TSTEPS - 1) * BATCH + b) * NO1 + no] = v;
}

// ---------------------------------------------------------------------------

extern "C" void kernel_launch(void* const* d_in, const int* in_sizes, int n_in,
                              void* d_out, int out_size, void* d_ws, size_t ws_size,
                              hipStream_t stream) {
    const float* inp   = (const float*)d_in[0];
    const int*   labels= (const int*)d_in[1];
    const float* Wi    = (const float*)d_in[2];
    const float* Wh    = (const float*)d_in[3];
    const float* b_lstm= (const float*)d_in[4];
    const float* Wf    = (const float*)d_in[5];
    const float* bf_   = (const float*)d_in[6];
    const float* Wb    = (const float*)d_in[7];
    const float* bwb   = (const float*)d_in[8];
    const float* ln_fs = (const float*)d_in[9];
    const float* ln_fb = (const float*)d_in[10];
    const float* ln_bs = (const float*)d_in[11];
    const float* ln_bb = (const float*)d_in[12];
    float* out = (float*)d_out;

    const size_t SZ0 = (size_t)BATCH * NO0 * 256 * 32;  // 8,388,608
    const size_t SZ1 = (size_t)BATCH * NO1 * 128 * 32;  // 2,097,152

    float* c0 = (float*)d_ws;
    float* c1 = c0 + SZ0;
    unsigned short* h0bf = (unsigned short*)(c1 + SZ1);
    unsigned short* h1bf = h0bf + SZ0;
    float* cm0         = (float*)(h1bf + SZ1);          // 524,288 f
    float* cm1         = cm0 + 524288;                  // 131,072 f
    unsigned short* hm0 = (unsigned short*)(cm1 + 131072);  // 524,288 us
    unsigned short* hm1 = hm0 + 524288;                 // 131,072 us
    float* bm_g        = (float*)(hm1 + 131072);        // 1,048,576 f
    float* nf_part     = bm_g + 1048576;                // 32,768 f
    float* nb1         = nf_part + 32768;               // 16,384 f
    float* outsum_part = nb1 + 16384;                   // 1,024 f
    float* gradP       = outsum_part + 1024;            // 512
    float* ohP         = gradP + 512;                   // 512
    unsigned short* WhBp = (unsigned short*)(ohP + 512);
    unsigned short* WfBp = WhBp + 4096;
    unsigned short* WbBp = WfBp + 512;
    unsigned short* WiFp = WbBp + 512;                  // 4096

    k_prep<<<36, 256, 0, stream>>>(Wh, Wf, Wb, Wi, WhBp, WfBp, WbBp, WiFp);

    for (int t = 0; t < TSTEPS; t++) {
        int l0grid = (t > 0) ? 2440 : 2048;   // +l1-merge +softmax(t-1)
        k_l0<<<l0grid, 256, 0, stream>>>(inp, Wi, WhBp, b_lstm, WfBp, bf_,
                                         ln_fs, ln_fb, h0bf, c0, hm0, cm0,
                                         (const unsigned int*)h1bf, c1, hm1, cm1,
                                         outsum_part, labels, out, gradP, ohP,
                                         nb1, nf_part, t);
        int l1grid = (t < TSTEPS - 1) ? 2560 : 1024;   // +l0-merge
        k_l1<<<l1grid, 256, 0, stream>>>(Wi, WhBp, b_lstm, WfBp, bf_,
                                         ln_fs, ln_fb, WbBp, bwb, ln_bs, ln_bb,
                                         WiFp, h1bf, c1, hm1, cm1,
                                         h0bf, c0, hm0, cm0,
                                         nf_part, gradP, ohP,
                                         bm_g, outsum_part, t);
        if (t < TSTEPS - 1)
            k_nb<<<64, 256, 0, stream>>>(bm_g, nb1);
    }
    k_fin<<<BATCH, 64, 0, stream>>>(outsum_part, out);
}

// Round 19
// 250.654 us; speedup vs baseline: 2.1893x; 2.1893x over previous
//
#include <hip/hip_runtime.h>
#include <hip/hip_bf16.h>

#define SLOW 32
#define MSG 16
#define TSTEPS 4
#define BATCH 8
#define NI0 256
#define NO0 128
#define NI1 128
#define NO1 64

typedef __bf16 bf16x8 __attribute__((ext_vector_type(8)));
typedef float f32x4 __attribute__((ext_vector_type(4)));

__device__ __forceinline__ float rcpf(float x) { return __builtin_amdgcn_rcpf(x); }
__device__ __forceinline__ float sigf(float x) { return rcpf(1.f + __expf(-x)); }
__device__ __forceinline__ float tanh_apx(float x) {
    float xc = fminf(fmaxf(x, -15.f), 15.f);
    float e = __expf(-2.f * xc);
    return (1.f - e) * rcpf(1.f + e);
}
__device__ __forceinline__ unsigned short f2bf(float x) {
    __bf16 h = (__bf16)x;
    return __builtin_bit_cast(unsigned short, h);
}
__device__ __forceinline__ float bf2f(unsigned short u) {
    __bf16 h = __builtin_bit_cast(__bf16, u);
    return (float)h;
}
__device__ __forceinline__ float sum16(float v) {
    v += __shfl_xor(v, 1); v += __shfl_xor(v, 2);
    v += __shfl_xor(v, 4); v += __shfl_xor(v, 8);
    return v;
}

// ---------------------------------------------------------------------------
// k_prep: pack B-fragments (bf16) for Wh (8 nt), Wf, Wb, Wi-fwd (8 nt, K pad)
// ---------------------------------------------------------------------------
__global__ void k_prep(const float* __restrict__ Wh, const float* __restrict__ Wf,
                       const float* __restrict__ Wb, const float* __restrict__ Wi,
                       unsigned short* __restrict__ WhBp,
                       unsigned short* __restrict__ WfBp,
                       unsigned short* __restrict__ WbBp,
                       unsigned short* __restrict__ WiFp) {
    int i = blockIdx.x * 256 + threadIdx.x;
    if (i < 4096) {
        int e = i & 7, l = (i >> 3) & 63, nt = i >> 9;
        int k = (l >> 4) * 8 + e, col = nt * 16 + (l & 15);
        WhBp[i] = f2bf(Wh[k * 128 + col]);
    } else if (i < 4608) {
        int j = i - 4096;
        int e = j & 7, l = j >> 3;
        int k = (l >> 4) * 8 + e;
        WfBp[j] = f2bf(Wf[k * 16 + (l & 15)]);
    } else if (i < 5120) {
        int j = i - 4608;
        int e = j & 7, l = j >> 3;
        int k = (l >> 4) * 8 + e;
        WbBp[j] = f2bf(Wb[k * 16 + (l & 15)]);
    } else if (i < 9216) {
        int j = i - 5120;
        int e = j & 7, l = (j >> 3) & 63, nt = j >> 9;
        int k = (l >> 4) * 8 + e, col = nt * 16 + (l & 15);
        WiFp[j] = (k < 16) ? f2bf(Wi[k * 128 + col]) : (unsigned short)0;
    }
}

// ---------------------------------------------------------------------------
// Layer 0 (+ overlapped l1-merge & softmax for the previous step):
//   blocks [0,2048)      : LSTM (b,no,q), 4 waves, 128 cells
//   blocks [2048,2304)   : hm1 merge (t>0)
//   blocks [2304,2432)   : cm1 merge (t>0)
//   blocks [2432,2440)   : softmax/error for step t-1 (t>0)
// NO waves-per-EU hint: r10 (64 VGPR) and r18 (40 VGPR) both proved the
// allocator spills catastrophically under any such cap. Plain 256 -> VGPR 88.
// ---------------------------------------------------------------------------
__global__ __launch_bounds__(256) void k_l0(
    const float* __restrict__ inp, const float* __restrict__ Wi,
    const unsigned short* __restrict__ WhBp, const float* __restrict__ b_lstm,
    const unsigned short* __restrict__ WfBp, const float* __restrict__ bf_,
    const float* __restrict__ ln_fs, const float* __restrict__ ln_fb,
    unsigned short* __restrict__ h0bf, float* __restrict__ c0g,
    const unsigned short* __restrict__ hm0, const float* __restrict__ cm0,
    const unsigned int* __restrict__ h1bf, const float* __restrict__ c1g,
    unsigned short* __restrict__ hm1, float* __restrict__ cm1,
    const float* __restrict__ outsum_part, const int* __restrict__ labels,
    float* __restrict__ dout, float* __restrict__ gradP, float* __restrict__ ohP,
    const float* __restrict__ nb1, float* __restrict__ nf_part, int t) {
    int tid = threadIdx.x;
    if (blockIdx.x >= 2048) {
        int mb = blockIdx.x - 2048;
        if (mb < 256) {   // hm1: 65536 u32 tasks
            int idx = mb * 256 + tid;
            int u = idx & 7, cell = (idx >> 3) & 127, no = idx >> 10;
            size_t base = ((size_t)no * 128 + cell) * 16 + u;
            const size_t strd = (size_t)NO1 * 128 * 16;
            float s0 = 0.f, s1 = 0.f;
#pragma unroll
            for (int b = 0; b < 8; b++) {
                unsigned int v = h1bf[base + b * strd];
                s0 += bf2f((unsigned short)(v & 0xffff));
                s1 += bf2f((unsigned short)(v >> 16));
            }
            ((unsigned int*)hm1)[((size_t)no * 128 + cell) * 8 + u] =
                (unsigned int)f2bf(s0 * 0.125f) | ((unsigned int)f2bf(s1 * 0.125f) << 16);
            return;
        }
        if (mb < 384) {   // cm1: 32768 float4 tasks
            int idx = (mb - 256) * 256 + tid;
            int s4 = idx & 3, cell = (idx >> 2) & 127, no = idx >> 9;
            const float4* C = (const float4*)c1g;
            size_t base = ((size_t)no * 128 + cell) * 8 + s4;
            const size_t strd = (size_t)NO1 * 128 * 8;
            float4 a = {0.f, 0.f, 0.f, 0.f};
#pragma unroll
            for (int b = 0; b < 8; b++) {
                float4 v = C[base + b * strd];
                a.x += v.x; a.y += v.y; a.z += v.z; a.w += v.w;
            }
            a.x *= 0.125f; a.y *= 0.125f; a.z *= 0.125f; a.w *= 0.125f;
            ((float4*)cm1)[((size_t)no * 128 + cell) * 4 + s4] = a;
            return;
        }
        {   // softmax for step t-1
            int b = mb - 384;
            int no = tid;
            if (no < 64) {
                float v = (outsum_part[((size_t)b * NO1 + no) * 2] +
                           outsum_part[((size_t)b * NO1 + no) * 2 + 1]) * (1.f / 128.f);
                float mx = v;
#pragma unroll
                for (int d = 1; d < 64; d <<= 1) mx = fmaxf(mx, __shfl_xor(mx, d));
                float e = __expf(v - mx);
                float sum = e;
#pragma unroll
                for (int d = 1; d < 64; d <<= 1) sum += __shfl_xor(sum, d);
                int lbl = labels[(t - 1) * BATCH + b];
                float oh = (no == lbl) ? 1.f : 0.f;
                gradP[b * NO1 + no] = e / sum - oh;
                ohP[b * NO1 + no] = oh;
                dout[((size_t)(t - 1) * BATCH + b) * NO1 + no] = v;
            }
            return;
        }
    }

    int q = blockIdx.x & 1;
    int no = (blockIdx.x >> 1) & 127;
    int b = blockIdx.x >> 8;
    int w = __builtin_amdgcn_readfirstlane(tid >> 6);
    int l = tid & 63, lo = l & 15, hg = l >> 4;
    const bool wb = (t < TSTEPS - 1);

    __shared__ unsigned short Hbf[128 * 40];
    __shared__ unsigned short BW[4096];
    __shared__ unsigned short BFr[512];
    __shared__ float gsh[128];
    __shared__ float mi_l[128];
    __shared__ float wi0[128];
    __shared__ float redn[4][16];

    {
        unsigned int* d = (unsigned int*)BW;
        const unsigned int* s = (const unsigned int*)WhBp;
#pragma unroll
        for (int i = tid; i < 2048; i += 256) d[i] = s[i];
        ((unsigned int*)BFr)[tid] = ((const unsigned int*)WfBp)[tid];
    }
    if (tid < 128) {
        float acc = b_lstm[tid];
        if (t > 0) {
            const float* nbr = nb1 + ((size_t)b * NO0 + no) * MSG;
#pragma unroll
            for (int m = 0; m < MSG; m++) acc += nbr[m] * Wi[(MSG + m) * 128 + tid];
        }
        gsh[tid] = acc;
        wi0[tid] = Wi[tid];
        mi_l[tid] = inp[((size_t)t * BATCH + b) * NI0 + q * 128 + tid];
    }
    {
        int lc = tid >> 1, half = tid & 1;
        unsigned int* hl = (unsigned int*)Hbf;
        if (t > 0) {
            if (half == 0) {
                const unsigned int* hsrc = (const unsigned int*)hm0 +
                    ((size_t)no * 256 + q * 128 + lc) * 8;
#pragma unroll
                for (int j = 0; j < 8; j++) hl[lc * 20 + j] = hsrc[j];
            } else {
                const unsigned int* hsrc = (const unsigned int*)h0bf +
                    ((size_t)(b * NO0 + no) * 256 + q * 128 + lc) * 16 + 8;
#pragma unroll
                for (int j = 0; j < 8; j++) hl[lc * 20 + 8 + j] = hsrc[j];
            }
        } else {
#pragma unroll
            for (int j = 0; j < 8; j++) hl[lc * 20 + half * 8 + j] = 0u;
        }
    }
    size_t cbase = (size_t)(b * NO0 + no) * 256 * 32;
    float cst[2][4][2];
    if (t > 0) {
#pragma unroll
        for (int mi_ = 0; mi_ < 2; mi_++)
#pragma unroll
            for (int r = 0; r < 4; r++) {
                int gc = q * 128 + (w * 2 + mi_) * 16 + hg * 4 + r;
                cst[mi_][r][0] = cm0[((size_t)no * 256 + gc) * 16 + lo];
                cst[mi_][r][1] = c0g[cbase + (size_t)gc * 32 + lo + 16];
            }
    } else {
#pragma unroll
        for (int mi_ = 0; mi_ < 2; mi_++)
#pragma unroll
            for (int r = 0; r < 4; r++) { cst[mi_][r][0] = 0.f; cst[mi_][r][1] = 0.f; }
    }
    __syncthreads();

    float g8[8], w8[8];
#pragma unroll
    for (int nt = 0; nt < 8; nt++) { g8[nt] = gsh[lo + 16 * nt]; w8[nt] = wi0[lo + 16 * nt]; }
    f32x4 miv[2];
#pragma unroll
    for (int mi_ = 0; mi_ < 2; mi_++)
#pragma unroll
        for (int r = 0; r < 4; r++)
            miv[mi_][r] = mi_l[(w * 2 + mi_) * 16 + hg * 4 + r];

#pragma unroll
    for (int micro = 0; micro < 2; micro++) {
#pragma unroll
        for (int mi_ = 0; mi_ < 2; mi_++) {
            int lt = w * 2 + mi_;
            bf16x8 A = *(const bf16x8*)&Hbf[(lt * 16 + lo) * 40 + hg * 8];
            f32x4 acc[4];
#pragma unroll
            for (int g = 0; g < 4; g++) {
                int nt = 2 * g;
                bf16x8 B = *(const bf16x8*)&BW[(nt * 64 + l) * 8];
                f32x4 ci = g8[nt] + miv[mi_] * w8[nt];
                acc[g] = __builtin_amdgcn_mfma_f32_16x16x32_bf16(A, B, ci, 0, 0, 0);
            }
#pragma unroll
            for (int r = 0; r < 4; r++) {
                int lrow = lt * 16 + hg * 4 + r;
                float cn = sigf(acc[1][r]) * cst[mi_][r][0] + sigf(acc[0][r]) * tanh_apx(acc[2][r]);
                cst[mi_][r][0] = cn;
                float hv = sigf(acc[3][r]) * tanh_apx(cn);
                Hbf[lrow * 40 + lo] = f2bf(hv);
                if (micro == 1 && wb)
                    c0g[cbase + (size_t)(q * 128 + lrow) * 32 + lo] = cn;
            }
#pragma unroll
            for (int g = 0; g < 4; g++) {
                int nt = 2 * g + 1;
                bf16x8 B = *(const bf16x8*)&BW[(nt * 64 + l) * 8];
                f32x4 ci = g8[nt] + miv[mi_] * w8[nt];
                acc[g] = __builtin_amdgcn_mfma_f32_16x16x32_bf16(A, B, ci, 0, 0, 0);
            }
#pragma unroll
            for (int r = 0; r < 4; r++) {
                int lrow = lt * 16 + hg * 4 + r;
                float cn = sigf(acc[1][r]) * cst[mi_][r][1] + sigf(acc[0][r]) * tanh_apx(acc[2][r]);
                cst[mi_][r][1] = cn;
                float hv = sigf(acc[3][r]) * tanh_apx(cn);
                Hbf[lrow * 40 + lo + 16] = f2bf(hv);
                if (micro == 1 && wb)
                    c0g[cbase + (size_t)(q * 128 + lrow) * 32 + lo + 16] = cn;
            }
        }
    }

    // epilogue: fm = LN(h @ Wf + bf); raw partial sums
    bf16x8 Ff = *(const bf16x8*)&BFr[l * 8];
    float lnfs = ln_fs[lo], lnfb = ln_fb[lo];
    float bfv = bf_[lo];
    f32x4 cif = {bfv, bfv, bfv, bfv};
    float nfp = 0.f;
#pragma unroll
    for (int mi_ = 0; mi_ < 2; mi_++) {
        int lt = w * 2 + mi_;
        bf16x8 A = *(const bf16x8*)&Hbf[(lt * 16 + lo) * 40 + hg * 8];
        f32x4 f = __builtin_amdgcn_mfma_f32_16x16x32_bf16(A, Ff, cif, 0, 0, 0);
#pragma unroll
        for (int r = 0; r < 4; r++) {
            float x = f[r];
            float mean = sum16(x) * 0.0625f;
            float d = x - mean;
            float rs = rsqrtf(sum16(d * d) * 0.0625f + 1e-6f);
            nfp += d * rs * lnfs + lnfb;
        }
    }
    nfp += __shfl_xor(nfp, 16);
    nfp += __shfl_xor(nfp, 32);
    if (l < 16) redn[w][l] = nfp;
    __syncthreads();
    if (tid < 16)
        nf_part[(((size_t)b * NO0 + no) * 2 + q) * 16 + tid] =
            redn[0][tid] + redn[1][tid] + redn[2][tid] + redn[3][tid];

    if (wb) {
        int lc = tid >> 1, part = tid & 1;
        unsigned int* hdst =
            (unsigned int*)h0bf +
            ((size_t)(b * NO0 + no) * 256 + q * 128 + lc) * 16 + part * 8;
        const unsigned int* hl = (const unsigned int*)Hbf;
#pragma unroll
        for (int j = 0; j < 8; j++) hdst[j] = hl[lc * 20 + part * 8 + j];
    }
}

// ---------------------------------------------------------------------------
// Layer 1: blocks [0,1024) = LSTM; blocks [1024,2560) = layer-0 merge.
// ---------------------------------------------------------------------------
__global__ __launch_bounds__(256) void k_l1(
    const float* __restrict__ Wi, const unsigned short* __restrict__ WhBp,
    const float* __restrict__ b_lstm,
    const unsigned short* __restrict__ WfBp, const float* __restrict__ bf_,
    const float* __restrict__ ln_fs, const float* __restrict__ ln_fb,
    const unsigned short* __restrict__ WbBp, const float* __restrict__ bwb,
    const float* __restrict__ ln_bs, const float* __restrict__ ln_bb,
    const unsigned short* __restrict__ WiFp,
    unsigned short* __restrict__ h1bf, float* __restrict__ c1g,
    const unsigned short* __restrict__ hm1, const float* __restrict__ cm1,
    const unsigned short* __restrict__ h0bf, const float* __restrict__ c0g,
    unsigned short* __restrict__ hm0, float* __restrict__ cm0,
    const float* __restrict__ nf_part, const float* __restrict__ gradP,
    const float* __restrict__ ohP,
    float* __restrict__ bm_g, float* __restrict__ outsum_part, int t) {
    int tid = threadIdx.x;
    if (blockIdx.x >= 1024) {
        int mb = blockIdx.x - 1024;
        if (mb < 1024) {  // hm0
            int idx = mb * 256 + tid;
            int u = idx & 7, cell = (idx >> 3) & 255, no = idx >> 11;
            size_t base = ((size_t)no * 256 + cell) * 16 + u;
            const size_t strd = (size_t)NO0 * 256 * 16;
            const unsigned int* H = (const unsigned int*)h0bf;
            float s0 = 0.f, s1 = 0.f;
#pragma unroll
            for (int b = 0; b < 8; b++) {
                unsigned int v = H[base + b * strd];
                s0 += bf2f((unsigned short)(v & 0xffff));
                s1 += bf2f((unsigned short)(v >> 16));
            }
            ((unsigned int*)hm0)[((size_t)no * 256 + cell) * 8 + u] =
                (unsigned int)f2bf(s0 * 0.125f) | ((unsigned int)f2bf(s1 * 0.125f) << 16);
        } else {          // cm0
            int idx = (mb - 1024) * 256 + tid;
            int s4 = idx & 3, cell = (idx >> 2) & 255, no = idx >> 10;
            const float4* C = (const float4*)c0g;
            size_t base = ((size_t)no * 256 + cell) * 8 + s4;
            const size_t strd = (size_t)NO0 * 256 * 8;
            float4 a = {0.f, 0.f, 0.f, 0.f};
#pragma unroll
            for (int b = 0; b < 8; b++) {
                float4 v = C[base + b * strd];
                a.x += v.x; a.y += v.y; a.z += v.z; a.w += v.w;
            }
            a.x *= 0.125f; a.y *= 0.125f; a.z *= 0.125f; a.w *= 0.125f;
            ((float4*)cm0)[((size_t)no * 256 + cell) * 4 + s4] = a;
        }
        return;
    }

    int q = blockIdx.x & 1;
    int no = (blockIdx.x >> 1) & 63;
    int b = blockIdx.x >> 7;
    int w = __builtin_amdgcn_readfirstlane(tid >> 6);
    int l = tid & 63, lo = l & 15, hg = l >> 4;
    const bool wb = (t < TSTEPS - 1);

    __shared__ unsigned short Hbf[64 * 40];
    __shared__ unsigned short BW[4096];
    __shared__ unsigned short WiF[4096];
    __shared__ unsigned short BFr[512];
    __shared__ unsigned short BBr[512];
    __shared__ float gsh[128];
    __shared__ float red[4];

    {
        unsigned int* d = (unsigned int*)BW;
        const unsigned int* s = (const unsigned int*)WhBp;
        unsigned int* d2 = (unsigned int*)WiF;
        const unsigned int* s2 = (const unsigned int*)WiFp;
#pragma unroll
        for (int i = tid; i < 2048; i += 256) { d[i] = s[i]; d2[i] = s2[i]; }
        ((unsigned int*)BFr)[tid] = ((const unsigned int*)WfBp)[tid];
        ((unsigned int*)BBr)[tid] = ((const unsigned int*)WbBp)[tid];
    }
    if (tid < 128) {
        float acc = b_lstm[tid];
        if (t > 0) {
            float g = gradP[b * NO1 + no], oh = ohP[b * NO1 + no];
            acc += g * Wi[MSG * 128 + tid] + oh * Wi[(MSG + 1) * 128 + tid];
        }
        gsh[tid] = acc;
    }
    {
        int lc = tid >> 2, part = tid & 3;
        unsigned int* hl = (unsigned int*)Hbf;
        if (t > 0) {
            if (part < 2) {
                const unsigned int* hsrc = (const unsigned int*)hm1 +
                    ((size_t)no * 128 + q * 64 + lc) * 8 + part * 4;
#pragma unroll
                for (int j = 0; j < 4; j++) hl[lc * 20 + part * 4 + j] = hsrc[j];
            } else {
                const unsigned int* hsrc = (const unsigned int*)h1bf +
                    ((size_t)(b * NO1 + no) * 128 + q * 64 + lc) * 16 + part * 4;
#pragma unroll
                for (int j = 0; j < 4; j++) hl[lc * 20 + part * 4 + j] = hsrc[j];
            }
        } else {
#pragma unroll
            for (int j = 0; j < 4; j++) hl[lc * 20 + part * 4 + j] = 0u;
        }
    }
    size_t cbase = (size_t)(b * NO1 + no) * 128 * 32;
    float cst[4][2];
    if (t > 0) {
#pragma unroll
        for (int r = 0; r < 4; r++) {
            int gc = q * 64 + w * 16 + hg * 4 + r;
            cst[r][0] = cm1[((size_t)no * 128 + gc) * 16 + lo];
            cst[r][1] = c1g[cbase + (size_t)gc * 32 + lo + 16];
        }
    } else {
#pragma unroll
        for (int r = 0; r < 4; r++) { cst[r][0] = 0.f; cst[r][1] = 0.f; }
    }
    bf16x8 Anf;
#pragma unroll
    for (int e = 0; e < 8; e++) Anf[e] = (__bf16)0.f;
    if (hg < 2) {
        const float* p = nf_part +
            ((size_t)b * 128 + q * 64 + w * 16 + lo) * 32 + hg * 8;
#pragma unroll
        for (int e = 0; e < 8; e++)
            Anf[e] = (__bf16)((p[e] + p[e + 16]) * (1.f / 256.f));
    }
    __syncthreads();

    f32x4 xf4[8];
    {
        f32x4 zz = {0.f, 0.f, 0.f, 0.f};
#pragma unroll
        for (int nt = 0; nt < 8; nt++) {
            bf16x8 B = *(const bf16x8*)&WiF[(nt * 64 + l) * 8];
            xf4[nt] = __builtin_amdgcn_mfma_f32_16x16x32_bf16(Anf, B, zz, 0, 0, 0);
        }
    }
    float g8[8];
#pragma unroll
    for (int nt = 0; nt < 8; nt++) g8[nt] = gsh[lo + 16 * nt];

#pragma unroll
    for (int micro = 0; micro < 2; micro++) {
        bf16x8 A = *(const bf16x8*)&Hbf[(w * 16 + lo) * 40 + hg * 8];
        f32x4 acc[4];
#pragma unroll
        for (int g = 0; g < 4; g++) {
            int nt = 2 * g;
            bf16x8 B = *(const bf16x8*)&BW[(nt * 64 + l) * 8];
            f32x4 ci = xf4[nt] + g8[nt];
            acc[g] = __builtin_amdgcn_mfma_f32_16x16x32_bf16(A, B, ci, 0, 0, 0);
        }
#pragma unroll
        for (int r = 0; r < 4; r++) {
            float cn = sigf(acc[1][r]) * cst[r][0] + sigf(acc[0][r]) * tanh_apx(acc[2][r]);
            cst[r][0] = cn;
            float hv = sigf(acc[3][r]) * tanh_apx(cn);
            Hbf[(w * 16 + hg * 4 + r) * 40 + lo] = f2bf(hv);
            if (micro == 1 && wb)
                c1g[cbase + (size_t)(q * 64 + w * 16 + hg * 4 + r) * 32 + lo] = cn;
        }
#pragma unroll
        for (int g = 0; g < 4; g++) {
            int nt = 2 * g + 1;
            bf16x8 B = *(const bf16x8*)&BW[(nt * 64 + l) * 8];
            f32x4 ci = xf4[nt] + g8[nt];
            acc[g] = __builtin_amdgcn_mfma_f32_16x16x32_bf16(A, B, ci, 0, 0, 0);
        }
#pragma unroll
        for (int r = 0; r < 4; r++) {
            float cn = sigf(acc[1][r]) * cst[r][1] + sigf(acc[0][r]) * tanh_apx(acc[2][r]);
            cst[r][1] = cn;
            float hv = sigf(acc[3][r]) * tanh_apx(cn);
            Hbf[(w * 16 + hg * 4 + r) * 40 + lo + 16] = f2bf(hv);
            if (micro == 1 && wb)
                c1g[cbase + (size_t)(q * 64 + w * 16 + hg * 4 + r) * 32 + lo + 16] = cn;
        }
    }

    bf16x8 Ff = *(const bf16x8*)&BFr[l * 8];
    float lnfs = ln_fs[lo], lnfb = ln_fb[lo];
    float bfv = bf_[lo];
    f32x4 cif = {bfv, bfv, bfv, bfv};
    float op = 0.f;
    {
        bf16x8 A = *(const bf16x8*)&Hbf[(w * 16 + lo) * 40 + hg * 8];
        f32x4 f = __builtin_amdgcn_mfma_f32_16x16x32_bf16(A, Ff, cif, 0, 0, 0);
#pragma unroll
        for (int r = 0; r < 4; r++) {
            float x = f[r];
            float mean = sum16(x) * 0.0625f;
            float d = x - mean;
            float rs = rsqrtf(sum16(d * d) * 0.0625f + 1e-6f);
            op += d * rs * lnfs + lnfb;
        }
        if (wb) {
            bf16x8 Bb = *(const bf16x8*)&BBr[l * 8];
            float lnbs = ln_bs[lo], lnbb = ln_bb[lo];
            float bwv = bwb[lo];
            f32x4 cib = {bwv, bwv, bwv, bwv};
            f32x4 g = __builtin_amdgcn_mfma_f32_16x16x32_bf16(A, Bb, cib, 0, 0, 0);
#pragma unroll
            for (int r = 0; r < 4; r++) {
                int gc = q * 64 + w * 16 + hg * 4 + r;
                float x = g[r];
                float mean = sum16(x) * 0.0625f;
                float d = x - mean;
                float rs = rsqrtf(sum16(d * d) * 0.0625f + 1e-6f);
                bm_g[(((size_t)b * NO1 + no) * MSG + lo) * NI1 + gc] = d * rs * lnbs + lnbb;
            }
        }
    }
    op += __shfl_xor(op, 16);
    op += __shfl_xor(op, 32);
    if (l == 0) red[w] = op;
    __syncthreads();
    if (tid == 0)
        outsum_part[((size_t)b * NO1 + no) * 2 + q] = red[0] + red[1] + red[2] + red[3];

    if (wb) {
        int lc = tid >> 2, part = tid & 3;
        unsigned int* hdst =
            (unsigned int*)h1bf +
            ((size_t)(b * NO1 + no) * 128 + q * 64 + lc) * 16 + part * 4;
        const unsigned int* hl = (const unsigned int*)Hbf;
#pragma unroll
        for (int j = 0; j < 4; j++) hdst[j] = hl[lc * 20 + part * 4 + j];
    }
}

// ---------------------------------------------------------------------------
// k_nb (t < TSTEPS-1): nb1[b][ni][m] = mean over no1 of bm_g
// ---------------------------------------------------------------------------
__global__ __launch_bounds__(256) void k_nb(const float* __restrict__ bm_g,
                                            float* __restrict__ nb1) {
    int g = blockIdx.x * 256 + threadIdx.x;  // < 16384
    int ni = g & 127;
    int m = (g >> 7) & 15;
    int b = g >> 11;
    float a = 0.f;
#pragma unroll 8
    for (int no = 0; no < NO1; no++)
        a += bm_g[(((size_t)b * NO1 + no) * MSG + m) * NI1 + ni];
    nb1[((size_t)b * NI1 + ni) * MSG + m] = a * (1.f / NO1);
}

// ---------------------------------------------------------------------------
// k_fin: final-step dout
// ---------------------------------------------------------------------------
__global__ void k_fin(const float* __restrict__ outsum_part,
                      float* __restrict__ dout) {
    int b = blockIdx.x;
    int no = threadIdx.x;
    float v = (outsum_part[((size_t)b * NO1 + no) * 2] +
               outsum_part[((size_t)b * NO1 + no) * 2 + 1]) * (1.f / 128.f);
    dout[((size_t)(TSTEPS - 1) * BATCH + b) * NO1 + no] = v;
}

// ---------------------------------------------------------------------------

extern "C" void kernel_launch(void* const* d_in, const int* in_sizes, int n_in,
                              void* d_out, int out_size, void* d_ws, size_t ws_size,
                              hipStream_t stream) {
    const float* inp   = (const float*)d_in[0];
    const int*   labels= (const int*)d_in[1];
    const float* Wi    = (const float*)d_in[2];
    const float* Wh    = (const float*)d_in[3];
    const float* b_lstm= (const float*)d_in[4];
    const float* Wf    = (const float*)d_in[5];
    const float* bf_   = (const float*)d_in[6];
    const float* Wb    = (const float*)d_in[7];
    const float* bwb   = (const float*)d_in[8];
    const float* ln_fs = (const float*)d_in[9];
    const float* ln_fb = (const float*)d_in[10];
    const float* ln_bs = (const float*)d_in[11];
    const float* ln_bb = (const float*)d_in[12];
    float* out = (float*)d_out;

    const size_t SZ0 = (size_t)BATCH * NO0 * 256 * 32;  // 8,388,608
    const size_t SZ1 = (size_t)BATCH * NO1 * 128 * 32;  // 2,097,152

    float* c0 = (float*)d_ws;
    float* c1 = c0 + SZ0;
    unsigned short* h0bf = (unsigned short*)(c1 + SZ1);
    unsigned short* h1bf = h0bf + SZ0;
    float* cm0         = (float*)(h1bf + SZ1);          // 524,288 f
    float* cm1         = cm0 + 524288;                  // 131,072 f
    unsigned short* hm0 = (unsigned short*)(cm1 + 131072);  // 524,288 us
    unsigned short* hm1 = hm0 + 524288;                 // 131,072 us
    float* bm_g        = (float*)(hm1 + 131072);        // 1,048,576 f
    float* nf_part     = bm_g + 1048576;                // 32,768 f
    float* nb1         = nf_part + 32768;               // 16,384 f
    float* outsum_part = nb1 + 16384;                   // 1,024 f
    float* gradP       = outsum_part + 1024;            // 512
    float* ohP         = gradP + 512;                   // 512
    unsigned short* WhBp = (unsigned short*)(ohP + 512);
    unsigned short* WfBp = WhBp + 4096;
    unsigned short* WbBp = WfBp + 512;
    unsigned short* WiFp = WbBp + 512;                  // 4096

    k_prep<<<36, 256, 0, stream>>>(Wh, Wf, Wb, Wi, WhBp, WfBp, WbBp, WiFp);

    for (int t = 0; t < TSTEPS; t++) {
        int l0grid = (t > 0) ? 2440 : 2048;   // +l1-merge +softmax(t-1)
        k_l0<<<l0grid, 256, 0, stream>>>(inp, Wi, WhBp, b_lstm, WfBp, bf_,
                                         ln_fs, ln_fb, h0bf, c0, hm0, cm0,
                                         (const unsigned int*)h1bf, c1, hm1, cm1,
                                         outsum_part, labels, out, gradP, ohP,
                                         nb1, nf_part, t);
        int l1grid = (t < TSTEPS - 1) ? 2560 : 1024;   // +l0-merge
        k_l1<<<l1grid, 256, 0, stream>>>(Wi, WhBp, b_lstm, WfBp, bf_,
                                         ln_fs, ln_fb, WbBp, bwb, ln_bs, ln_bb,
                                         WiFp, h1bf, c1, hm1, cm1,
                                         h0bf, c0, hm0, cm0,
                                         nf_part, gradP, ohP,
                                         bm_g, outsum_part, t);
        if (t < TSTEPS - 1)
            k_nb<<<64, 256, 0, stream>>>(bm_g, nb1);
    }
    k_fin<<<BATCH, 64, 0, stream>>>(outsum_part, out);
}

// Round 20
// 245.977 us; speedup vs baseline: 2.2309x; 1.0190x over previous
//
#include <hip/hip_runtime.h>
#include <hip/hip_bf16.h>

#define SLOW 32
#define MSG 16
#define TSTEPS 4
#define BATCH 8
#define NI0 256
#define NO0 128
#define NI1 128
#define NO1 64

typedef __bf16 bf16x8 __attribute__((ext_vector_type(8)));
typedef float f32x4 __attribute__((ext_vector_type(4)));

__device__ __forceinline__ float rcpf(float x) { return __builtin_amdgcn_rcpf(x); }
__device__ __forceinline__ float sigf(float x) { return rcpf(1.f + __expf(-x)); }
__device__ __forceinline__ float tanh_apx(float x) {
    float xc = fminf(fmaxf(x, -15.f), 15.f);
    float e = __expf(-2.f * xc);
    return (1.f - e) * rcpf(1.f + e);
}
__device__ __forceinline__ unsigned short f2bf(float x) {
    __bf16 h = (__bf16)x;
    return __builtin_bit_cast(unsigned short, h);
}
__device__ __forceinline__ float bf2f(unsigned short u) {
    __bf16 h = __builtin_bit_cast(__bf16, u);
    return (float)h;
}
__device__ __forceinline__ float sum16(float v) {
    v += __shfl_xor(v, 1); v += __shfl_xor(v, 2);
    v += __shfl_xor(v, 4); v += __shfl_xor(v, 8);
    return v;
}

// ---------------------------------------------------------------------------
// k_prep: pack B-fragments (bf16) for Wh (8 nt), Wf, Wb, Wi-fwd (8 nt, K pad)
// ---------------------------------------------------------------------------
__global__ void k_prep(const float* __restrict__ Wh, const float* __restrict__ Wf,
                       const float* __restrict__ Wb, const float* __restrict__ Wi,
                       unsigned short* __restrict__ WhBp,
                       unsigned short* __restrict__ WfBp,
                       unsigned short* __restrict__ WbBp,
                       unsigned short* __restrict__ WiFp) {
    int i = blockIdx.x * 256 + threadIdx.x;
    if (i < 4096) {
        int e = i & 7, l = (i >> 3) & 63, nt = i >> 9;
        int k = (l >> 4) * 8 + e, col = nt * 16 + (l & 15);
        WhBp[i] = f2bf(Wh[k * 128 + col]);
    } else if (i < 4608) {
        int j = i - 4096;
        int e = j & 7, l = j >> 3;
        int k = (l >> 4) * 8 + e;
        WfBp[j] = f2bf(Wf[k * 16 + (l & 15)]);
    } else if (i < 5120) {
        int j = i - 4608;
        int e = j & 7, l = j >> 3;
        int k = (l >> 4) * 8 + e;
        WbBp[j] = f2bf(Wb[k * 16 + (l & 15)]);
    } else if (i < 9216) {
        int j = i - 5120;
        int e = j & 7, l = (j >> 3) & 63, nt = j >> 9;
        int k = (l >> 4) * 8 + e, col = nt * 16 + (l & 15);
        WiFp[j] = (k < 16) ? f2bf(Wi[k * 128 + col]) : (unsigned short)0;
    }
}

// ---------------------------------------------------------------------------
// Layer 0 (+ overlapped l1-merge & softmax riders).
// Wh B-fragments hoisted to per-lane REGISTERS (read once from L2, reused
// 16x); Wf fragment read from global at use. No BW/BFr LDS, no staging loop.
// ---------------------------------------------------------------------------
__global__ __launch_bounds__(256) void k_l0(
    const float* __restrict__ inp, const float* __restrict__ Wi,
    const unsigned short* __restrict__ WhBp, const float* __restrict__ b_lstm,
    const unsigned short* __restrict__ WfBp, const float* __restrict__ bf_,
    const float* __restrict__ ln_fs, const float* __restrict__ ln_fb,
    unsigned short* __restrict__ h0bf, float* __restrict__ c0g,
    const unsigned short* __restrict__ hm0, const float* __restrict__ cm0,
    const unsigned int* __restrict__ h1bf, const float* __restrict__ c1g,
    unsigned short* __restrict__ hm1, float* __restrict__ cm1,
    const float* __restrict__ outsum_part, const int* __restrict__ labels,
    float* __restrict__ dout, float* __restrict__ gradP, float* __restrict__ ohP,
    const float* __restrict__ nb1, float* __restrict__ nf_part, int t) {
    int tid = threadIdx.x;
    if (blockIdx.x >= 2048) {
        int mb = blockIdx.x - 2048;
        if (mb < 256) {   // hm1
            int idx = mb * 256 + tid;
            int u = idx & 7, cell = (idx >> 3) & 127, no = idx >> 10;
            size_t base = ((size_t)no * 128 + cell) * 16 + u;
            const size_t strd = (size_t)NO1 * 128 * 16;
            float s0 = 0.f, s1 = 0.f;
#pragma unroll
            for (int b = 0; b < 8; b++) {
                unsigned int v = h1bf[base + b * strd];
                s0 += bf2f((unsigned short)(v & 0xffff));
                s1 += bf2f((unsigned short)(v >> 16));
            }
            ((unsigned int*)hm1)[((size_t)no * 128 + cell) * 8 + u] =
                (unsigned int)f2bf(s0 * 0.125f) | ((unsigned int)f2bf(s1 * 0.125f) << 16);
            return;
        }
        if (mb < 384) {   // cm1
            int idx = (mb - 256) * 256 + tid;
            int s4 = idx & 3, cell = (idx >> 2) & 127, no = idx >> 9;
            const float4* C = (const float4*)c1g;
            size_t base = ((size_t)no * 128 + cell) * 8 + s4;
            const size_t strd = (size_t)NO1 * 128 * 8;
            float4 a = {0.f, 0.f, 0.f, 0.f};
#pragma unroll
            for (int b = 0; b < 8; b++) {
                float4 v = C[base + b * strd];
                a.x += v.x; a.y += v.y; a.z += v.z; a.w += v.w;
            }
            a.x *= 0.125f; a.y *= 0.125f; a.z *= 0.125f; a.w *= 0.125f;
            ((float4*)cm1)[((size_t)no * 128 + cell) * 4 + s4] = a;
            return;
        }
        {   // softmax for step t-1
            int b = mb - 384;
            int no = tid;
            if (no < 64) {
                float v = (outsum_part[((size_t)b * NO1 + no) * 2] +
                           outsum_part[((size_t)b * NO1 + no) * 2 + 1]) * (1.f / 128.f);
                float mx = v;
#pragma unroll
                for (int d = 1; d < 64; d <<= 1) mx = fmaxf(mx, __shfl_xor(mx, d));
                float e = __expf(v - mx);
                float sum = e;
#pragma unroll
                for (int d = 1; d < 64; d <<= 1) sum += __shfl_xor(sum, d);
                int lbl = labels[(t - 1) * BATCH + b];
                float oh = (no == lbl) ? 1.f : 0.f;
                gradP[b * NO1 + no] = e / sum - oh;
                ohP[b * NO1 + no] = oh;
                dout[((size_t)(t - 1) * BATCH + b) * NO1 + no] = v;
            }
            return;
        }
    }

    int q = blockIdx.x & 1;
    int no = (blockIdx.x >> 1) & 127;
    int b = blockIdx.x >> 8;
    int w = __builtin_amdgcn_readfirstlane(tid >> 6);
    int l = tid & 63, lo = l & 15, hg = l >> 4;
    const bool wb = (t < TSTEPS - 1);

    __shared__ unsigned short Hbf[128 * 40];
    __shared__ float gsh[128];
    __shared__ float mi_l[128];
    __shared__ float wi0[128];
    __shared__ float redn[4][16];

    // B-fragments of Wh: per-lane registers, read once (L2-hot, coalesced)
    bf16x8 BWr[8];
#pragma unroll
    for (int nt = 0; nt < 8; nt++)
        BWr[nt] = *(const bf16x8*)&WhBp[(nt * 64 + l) * 8];

    if (tid < 128) {
        float acc = b_lstm[tid];
        if (t > 0) {
            const float* nbr = nb1 + ((size_t)b * NO0 + no) * MSG;
#pragma unroll
            for (int m = 0; m < MSG; m++) acc += nbr[m] * Wi[(MSG + m) * 128 + tid];
        }
        gsh[tid] = acc;
        wi0[tid] = Wi[tid];
        mi_l[tid] = inp[((size_t)t * BATCH + b) * NI0 + q * 128 + tid];
    }
    {
        int lc = tid >> 1, half = tid & 1;
        unsigned int* hl = (unsigned int*)Hbf;
        if (t > 0) {
            if (half == 0) {
                const unsigned int* hsrc = (const unsigned int*)hm0 +
                    ((size_t)no * 256 + q * 128 + lc) * 8;
#pragma unroll
                for (int j = 0; j < 8; j++) hl[lc * 20 + j] = hsrc[j];
            } else {
                const unsigned int* hsrc = (const unsigned int*)h0bf +
                    ((size_t)(b * NO0 + no) * 256 + q * 128 + lc) * 16 + 8;
#pragma unroll
                for (int j = 0; j < 8; j++) hl[lc * 20 + 8 + j] = hsrc[j];
            }
        } else {
#pragma unroll
            for (int j = 0; j < 8; j++) hl[lc * 20 + half * 8 + j] = 0u;
        }
    }
    size_t cbase = (size_t)(b * NO0 + no) * 256 * 32;
    float cst[2][4][2];
    if (t > 0) {
#pragma unroll
        for (int mi_ = 0; mi_ < 2; mi_++)
#pragma unroll
            for (int r = 0; r < 4; r++) {
                int gc = q * 128 + (w * 2 + mi_) * 16 + hg * 4 + r;
                cst[mi_][r][0] = cm0[((size_t)no * 256 + gc) * 16 + lo];
                cst[mi_][r][1] = c0g[cbase + (size_t)gc * 32 + lo + 16];
            }
    } else {
#pragma unroll
        for (int mi_ = 0; mi_ < 2; mi_++)
#pragma unroll
            for (int r = 0; r < 4; r++) { cst[mi_][r][0] = 0.f; cst[mi_][r][1] = 0.f; }
    }
    __syncthreads();

    float g8[8], w8[8];
#pragma unroll
    for (int nt = 0; nt < 8; nt++) { g8[nt] = gsh[lo + 16 * nt]; w8[nt] = wi0[lo + 16 * nt]; }
    f32x4 miv[2];
#pragma unroll
    for (int mi_ = 0; mi_ < 2; mi_++)
#pragma unroll
        for (int r = 0; r < 4; r++)
            miv[mi_][r] = mi_l[(w * 2 + mi_) * 16 + hg * 4 + r];

#pragma unroll
    for (int micro = 0; micro < 2; micro++) {
#pragma unroll
        for (int mi_ = 0; mi_ < 2; mi_++) {
            int lt = w * 2 + mi_;
            bf16x8 A = *(const bf16x8*)&Hbf[(lt * 16 + lo) * 40 + hg * 8];
            f32x4 acc[4];
#pragma unroll
            for (int g = 0; g < 4; g++) {
                f32x4 ci = g8[2 * g] + miv[mi_] * w8[2 * g];
                acc[g] = __builtin_amdgcn_mfma_f32_16x16x32_bf16(A, BWr[2 * g], ci, 0, 0, 0);
            }
#pragma unroll
            for (int r = 0; r < 4; r++) {
                int lrow = lt * 16 + hg * 4 + r;
                float cn = sigf(acc[1][r]) * cst[mi_][r][0] + sigf(acc[0][r]) * tanh_apx(acc[2][r]);
                cst[mi_][r][0] = cn;
                float hv = sigf(acc[3][r]) * tanh_apx(cn);
                Hbf[lrow * 40 + lo] = f2bf(hv);
                if (micro == 1 && wb)
                    c0g[cbase + (size_t)(q * 128 + lrow) * 32 + lo] = cn;
            }
#pragma unroll
            for (int g = 0; g < 4; g++) {
                f32x4 ci = g8[2 * g + 1] + miv[mi_] * w8[2 * g + 1];
                acc[g] = __builtin_amdgcn_mfma_f32_16x16x32_bf16(A, BWr[2 * g + 1], ci, 0, 0, 0);
            }
#pragma unroll
            for (int r = 0; r < 4; r++) {
                int lrow = lt * 16 + hg * 4 + r;
                float cn = sigf(acc[1][r]) * cst[mi_][r][1] + sigf(acc[0][r]) * tanh_apx(acc[2][r]);
                cst[mi_][r][1] = cn;
                float hv = sigf(acc[3][r]) * tanh_apx(cn);
                Hbf[lrow * 40 + lo + 16] = f2bf(hv);
                if (micro == 1 && wb)
                    c0g[cbase + (size_t)(q * 128 + lrow) * 32 + lo + 16] = cn;
            }
        }
    }

    // epilogue: fm = LN(h @ Wf + bf); Wf fragment read from global (1 use)
    bf16x8 Ff = *(const bf16x8*)&WfBp[l * 8];
    float lnfs = ln_fs[lo], lnfb = ln_fb[lo];
    float bfv = bf_[lo];
    f32x4 cif = {bfv, bfv, bfv, bfv};
    float nfp = 0.f;
#pragma unroll
    for (int mi_ = 0; mi_ < 2; mi_++) {
        int lt = w * 2 + mi_;
        bf16x8 A = *(const bf16x8*)&Hbf[(lt * 16 + lo) * 40 + hg * 8];
        f32x4 f = __builtin_amdgcn_mfma_f32_16x16x32_bf16(A, Ff, cif, 0, 0, 0);
#pragma unroll
        for (int r = 0; r < 4; r++) {
            float x = f[r];
            float mean = sum16(x) * 0.0625f;
            float d = x - mean;
            float rs = rsqrtf(sum16(d * d) * 0.0625f + 1e-6f);
            nfp += d * rs * lnfs + lnfb;
        }
    }
    nfp += __shfl_xor(nfp, 16);
    nfp += __shfl_xor(nfp, 32);
    if (l < 16) redn[w][l] = nfp;
    __syncthreads();
    if (tid < 16)
        nf_part[(((size_t)b * NO0 + no) * 2 + q) * 16 + tid] =
            redn[0][tid] + redn[1][tid] + redn[2][tid] + redn[3][tid];

    if (wb) {
        int lc = tid >> 1, part = tid & 1;
        unsigned int* hdst =
            (unsigned int*)h0bf +
            ((size_t)(b * NO0 + no) * 256 + q * 128 + lc) * 16 + part * 8;
        const unsigned int* hl = (const unsigned int*)Hbf;
#pragma unroll
        for (int j = 0; j < 8; j++) hdst[j] = hl[lc * 20 + part * 8 + j];
    }
}

// ---------------------------------------------------------------------------
// Layer 1: blocks [0,1024) = LSTM (BW hoisted to regs; WiF/BFr/BBr from
// global at use); blocks [1024,2560) = layer-0 merge riders.
// ---------------------------------------------------------------------------
__global__ __launch_bounds__(256) void k_l1(
    const float* __restrict__ Wi, const unsigned short* __restrict__ WhBp,
    const float* __restrict__ b_lstm,
    const unsigned short* __restrict__ WfBp, const float* __restrict__ bf_,
    const float* __restrict__ ln_fs, const float* __restrict__ ln_fb,
    const unsigned short* __restrict__ WbBp, const float* __restrict__ bwb,
    const float* __restrict__ ln_bs, const float* __restrict__ ln_bb,
    const unsigned short* __restrict__ WiFp,
    unsigned short* __restrict__ h1bf, float* __restrict__ c1g,
    const unsigned short* __restrict__ hm1, const float* __restrict__ cm1,
    const unsigned short* __restrict__ h0bf, const float* __restrict__ c0g,
    unsigned short* __restrict__ hm0, float* __restrict__ cm0,
    const float* __restrict__ nf_part, const float* __restrict__ gradP,
    const float* __restrict__ ohP,
    float* __restrict__ bm_g, float* __restrict__ outsum_part, int t) {
    int tid = threadIdx.x;
    if (blockIdx.x >= 1024) {
        int mb = blockIdx.x - 1024;
        if (mb < 1024) {  // hm0
            int idx = mb * 256 + tid;
            int u = idx & 7, cell = (idx >> 3) & 255, no = idx >> 11;
            size_t base = ((size_t)no * 256 + cell) * 16 + u;
            const size_t strd = (size_t)NO0 * 256 * 16;
            const unsigned int* H = (const unsigned int*)h0bf;
            float s0 = 0.f, s1 = 0.f;
#pragma unroll
            for (int b = 0; b < 8; b++) {
                unsigned int v = H[base + b * strd];
                s0 += bf2f((unsigned short)(v & 0xffff));
                s1 += bf2f((unsigned short)(v >> 16));
            }
            ((unsigned int*)hm0)[((size_t)no * 256 + cell) * 8 + u] =
                (unsigned int)f2bf(s0 * 0.125f) | ((unsigned int)f2bf(s1 * 0.125f) << 16);
        } else {          // cm0
            int idx = (mb - 1024) * 256 + tid;
            int s4 = idx & 3, cell = (idx >> 2) & 255, no = idx >> 10;
            const float4* C = (const float4*)c0g;
            size_t base = ((size_t)no * 256 + cell) * 8 + s4;
            const size_t strd = (size_t)NO0 * 256 * 8;
            float4 a = {0.f, 0.f, 0.f, 0.f};
#pragma unroll
            for (int b = 0; b < 8; b++) {
                float4 v = C[base + b * strd];
                a.x += v.x; a.y += v.y; a.z += v.z; a.w += v.w;
            }
            a.x *= 0.125f; a.y *= 0.125f; a.z *= 0.125f; a.w *= 0.125f;
            ((float4*)cm0)[((size_t)no * 256 + cell) * 4 + s4] = a;
        }
        return;
    }

    int q = blockIdx.x & 1;
    int no = (blockIdx.x >> 1) & 63;
    int b = blockIdx.x >> 7;
    int w = __builtin_amdgcn_readfirstlane(tid >> 6);
    int l = tid & 63, lo = l & 15, hg = l >> 4;
    const bool wb = (t < TSTEPS - 1);

    __shared__ unsigned short Hbf[64 * 40];
    __shared__ float gsh[128];
    __shared__ float red[4];

    bf16x8 BWr[8];
#pragma unroll
    for (int nt = 0; nt < 8; nt++)
        BWr[nt] = *(const bf16x8*)&WhBp[(nt * 64 + l) * 8];

    if (tid < 128) {
        float acc = b_lstm[tid];
        if (t > 0) {
            float g = gradP[b * NO1 + no], oh = ohP[b * NO1 + no];
            acc += g * Wi[MSG * 128 + tid] + oh * Wi[(MSG + 1) * 128 + tid];
        }
        gsh[tid] = acc;
    }
    {
        int lc = tid >> 2, part = tid & 3;
        unsigned int* hl = (unsigned int*)Hbf;
        if (t > 0) {
            if (part < 2) {
                const unsigned int* hsrc = (const unsigned int*)hm1 +
                    ((size_t)no * 128 + q * 64 + lc) * 8 + part * 4;
#pragma unroll
                for (int j = 0; j < 4; j++) hl[lc * 20 + part * 4 + j] = hsrc[j];
            } else {
                const unsigned int* hsrc = (const unsigned int*)h1bf +
                    ((size_t)(b * NO1 + no) * 128 + q * 64 + lc) * 16 + part * 4;
#pragma unroll
                for (int j = 0; j < 4; j++) hl[lc * 20 + part * 4 + j] = hsrc[j];
            }
        } else {
#pragma unroll
            for (int j = 0; j < 4; j++) hl[lc * 20 + part * 4 + j] = 0u;
        }
    }
    size_t cbase = (size_t)(b * NO1 + no) * 128 * 32;
    float cst[4][2];
    if (t > 0) {
#pragma unroll
        for (int r = 0; r < 4; r++) {
            int gc = q * 64 + w * 16 + hg * 4 + r;
            cst[r][0] = cm1[((size_t)no * 128 + gc) * 16 + lo];
            cst[r][1] = c1g[cbase + (size_t)gc * 32 + lo + 16];
        }
    } else {
#pragma unroll
        for (int r = 0; r < 4; r++) { cst[r][0] = 0.f; cst[r][1] = 0.f; }
    }
    bf16x8 Anf;
#pragma unroll
    for (int e = 0; e < 8; e++) Anf[e] = (__bf16)0.f;
    if (hg < 2) {
        const float* p = nf_part +
            ((size_t)b * 128 + q * 64 + w * 16 + lo) * 32 + hg * 8;
#pragma unroll
        for (int e = 0; e < 8; e++)
            Anf[e] = (__bf16)((p[e] + p[e + 16]) * (1.f / 256.f));
    }
    __syncthreads();

    // xf via MFMA; WiF fragments from global (single use each)
    f32x4 xf4[8];
    {
        f32x4 zz = {0.f, 0.f, 0.f, 0.f};
#pragma unroll
        for (int nt = 0; nt < 8; nt++) {
            bf16x8 B = *(const bf16x8*)&WiFp[(nt * 64 + l) * 8];
            xf4[nt] = __builtin_amdgcn_mfma_f32_16x16x32_bf16(Anf, B, zz, 0, 0, 0);
        }
    }
    float g8[8];
#pragma unroll
    for (int nt = 0; nt < 8; nt++) g8[nt] = gsh[lo + 16 * nt];

#pragma unroll
    for (int micro = 0; micro < 2; micro++) {
        bf16x8 A = *(const bf16x8*)&Hbf[(w * 16 + lo) * 40 + hg * 8];
        f32x4 acc[4];
#pragma unroll
        for (int g = 0; g < 4; g++) {
            f32x4 ci = xf4[2 * g] + g8[2 * g];
            acc[g] = __builtin_amdgcn_mfma_f32_16x16x32_bf16(A, BWr[2 * g], ci, 0, 0, 0);
        }
#pragma unroll
        for (int r = 0; r < 4; r++) {
            float cn = sigf(acc[1][r]) * cst[r][0] + sigf(acc[0][r]) * tanh_apx(acc[2][r]);
            cst[r][0] = cn;
            float hv = sigf(acc[3][r]) * tanh_apx(cn);
            Hbf[(w * 16 + hg * 4 + r) * 40 + lo] = f2bf(hv);
            if (micro == 1 && wb)
                c1g[cbase + (size_t)(q * 64 + w * 16 + hg * 4 + r) * 32 + lo] = cn;
        }
#pragma unroll
        for (int g = 0; g < 4; g++) {
            f32x4 ci = xf4[2 * g + 1] + g8[2 * g + 1];
            acc[g] = __builtin_amdgcn_mfma_f32_16x16x32_bf16(A, BWr[2 * g + 1], ci, 0, 0, 0);
        }
#pragma unroll
        for (int r = 0; r < 4; r++) {
            float cn = sigf(acc[1][r]) * cst[r][1] + sigf(acc[0][r]) * tanh_apx(acc[2][r]);
            cst[r][1] = cn;
            float hv = sigf(acc[3][r]) * tanh_apx(cn);
            Hbf[(w * 16 + hg * 4 + r) * 40 + lo + 16] = f2bf(hv);
            if (micro == 1 && wb)
                c1g[cbase + (size_t)(q * 64 + w * 16 + hg * 4 + r) * 32 + lo + 16] = cn;
        }
    }

    // epilogue: Wf/Wb fragments from global (single use)
    bf16x8 Ff = *(const bf16x8*)&WfBp[l * 8];
    float lnfs = ln_fs[lo], lnfb = ln_fb[lo];
    float bfv = bf_[lo];
    f32x4 cif = {bfv, bfv, bfv, bfv};
    float op = 0.f;
    {
        bf16x8 A = *(const bf16x8*)&Hbf[(w * 16 + lo) * 40 + hg * 8];
        f32x4 f = __builtin_amdgcn_mfma_f32_16x16x32_bf16(A, Ff, cif, 0, 0, 0);
#pragma unroll
        for (int r = 0; r < 4; r++) {
            float x = f[r];
            float mean = sum16(x) * 0.0625f;
            float d = x - mean;
            float rs = rsqrtf(sum16(d * d) * 0.0625f + 1e-6f);
            op += d * rs * lnfs + lnfb;
        }
        if (wb) {
            bf16x8 Bb = *(const bf16x8*)&WbBp[l * 8];
            float lnbs = ln_bs[lo], lnbb = ln_bb[lo];
            float bwv = bwb[lo];
            f32x4 cib = {bwv, bwv, bwv, bwv};
            f32x4 g = __builtin_amdgcn_mfma_f32_16x16x32_bf16(A, Bb, cib, 0, 0, 0);
#pragma unroll
            for (int r = 0; r < 4; r++) {
                int gc = q * 64 + w * 16 + hg * 4 + r;
                float x = g[r];
                float mean = sum16(x) * 0.0625f;
                float d = x - mean;
                float rs = rsqrtf(sum16(d * d) * 0.0625f + 1e-6f);
                bm_g[(((size_t)b * NO1 + no) * MSG + lo) * NI1 + gc] = d * rs * lnbs + lnbb;
            }
        }
    }
    op += __shfl_xor(op, 16);
    op += __shfl_xor(op, 32);
    if (l == 0) red[w] = op;
    __syncthreads();
    if (tid == 0)
        outsum_part[((size_t)b * NO1 + no) * 2 + q] = red[0] + red[1] + red[2] + red[3];

    if (wb) {
        int lc = tid >> 2, part = tid & 3;
        unsigned int* hdst =
            (unsigned int*)h1bf +
            ((size_t)(b * NO1 + no) * 128 + q * 64 + lc) * 16 + part * 4;
        const unsigned int* hl = (const unsigned int*)Hbf;
#pragma unroll
        for (int j = 0; j < 4; j++) hdst[j] = hl[lc * 20 + part * 4 + j];
    }
}

// ---------------------------------------------------------------------------
// k_nb (t < TSTEPS-1): nb1[b][ni][m] = mean over no1 of bm_g
// ---------------------------------------------------------------------------
__global__ __launch_bounds__(256) void k_nb(const float* __restrict__ bm_g,
                                            float* __restrict__ nb1) {
    int g = blockIdx.x * 256 + threadIdx.x;  // < 16384
    int ni = g & 127;
    int m = (g >> 7) & 15;
    int b = g >> 11;
    float a = 0.f;
#pragma unroll 8
    for (int no = 0; no < NO1; no++)
        a += bm_g[(((size_t)b * NO1 + no) * MSG + m) * NI1 + ni];
    nb1[((size_t)b * NI1 + ni) * MSG + m] = a * (1.f / NO1);
}

// ---------------------------------------------------------------------------
// k_fin: final-step dout
// ---------------------------------------------------------------------------
__global__ void k_fin(const float* __restrict__ outsum_part,
                      float* __restrict__ dout) {
    int b = blockIdx.x;
    int no = threadIdx.x;
    float v = (outsum_part[((size_t)b * NO1 + no) * 2] +
               outsum_part[((size_t)b * NO1 + no) * 2 + 1]) * (1.f / 128.f);
    dout[((size_t)(TSTEPS - 1) * BATCH + b) * NO1 + no] = v;
}

// ---------------------------------------------------------------------------

extern "C" void kernel_launch(void* const* d_in, const int* in_sizes, int n_in,
                              void* d_out, int out_size, void* d_ws, size_t ws_size,
                              hipStream_t stream) {
    const float* inp   = (const float*)d_in[0];
    const int*   labels= (const int*)d_in[1];
    const float* Wi    = (const float*)d_in[2];
    const float* Wh    = (const float*)d_in[3];
    const float* b_lstm= (const float*)d_in[4];
    const float* Wf    = (const float*)d_in[5];
    const float* bf_   = (const float*)d_in[6];
    const float* Wb    = (const float*)d_in[7];
    const float* bwb   = (const float*)d_in[8];
    const float* ln_fs = (const float*)d_in[9];
    const float* ln_fb = (const float*)d_in[10];
    const float* ln_bs = (const float*)d_in[11];
    const float* ln_bb = (const float*)d_in[12];
    float* out = (float*)d_out;

    const size_t SZ0 = (size_t)BATCH * NO0 * 256 * 32;  // 8,388,608
    const size_t SZ1 = (size_t)BATCH * NO1 * 128 * 32;  // 2,097,152

    float* c0 = (float*)d_ws;
    float* c1 = c0 + SZ0;
    unsigned short* h0bf = (unsigned short*)(c1 + SZ1);
    unsigned short* h1bf = h0bf + SZ0;
    float* cm0         = (float*)(h1bf + SZ1);          // 524,288 f
    float* cm1         = cm0 + 524288;                  // 131,072 f
    unsigned short* hm0 = (unsigned short*)(cm1 + 131072);  // 524,288 us
    unsigned short* hm1 = hm0 + 524288;                 // 131,072 us
    float* bm_g        = (float*)(hm1 + 131072);        // 1,048,576 f
    float* nf_part     = bm_g + 1048576;                // 32,768 f
    float* nb1         = nf_part + 32768;               // 16,384 f
    float* outsum_part = nb1 + 16384;                   // 1,024 f
    float* gradP       = outsum_part + 1024;            // 512
    float* ohP         = gradP + 512;                   // 512
    unsigned short* WhBp = (unsigned short*)(ohP + 512);
    unsigned short* WfBp = WhBp + 4096;
    unsigned short* WbBp = WfBp + 512;
    unsigned short* WiFp = WbBp + 512;                  // 4096

    k_prep<<<36, 256, 0, stream>>>(Wh, Wf, Wb, Wi, WhBp, WfBp, WbBp, WiFp);

    for (int t = 0; t < TSTEPS; t++) {
        int l0grid = (t > 0) ? 2440 : 2048;
        k_l0<<<l0grid, 256, 0, stream>>>(inp, Wi, WhBp, b_lstm, WfBp, bf_,
                                         ln_fs, ln_fb, h0bf, c0, hm0, cm0,
                                         (const unsigned int*)h1bf, c1, hm1, cm1,
                                         outsum_part, labels, out, gradP, ohP,
                                         nb1, nf_part, t);
        int l1grid = (t < TSTEPS - 1) ? 2560 : 1024;
        k_l1<<<l1grid, 256, 0, stream>>>(Wi, WhBp, b_lstm, WfBp, bf_,
                                         ln_fs, ln_fb, WbBp, bwb, ln_bs, ln_bb,
                                         WiFp, h1bf, c1, hm1, cm1,
                                         h0bf, c0, hm0, cm0,
                                         nf_part, gradP, ohP,
                                         bm_g, outsum_part, t);
        if (t < TSTEPS - 1)
            k_nb<<<64, 256, 0, stream>>>(bm_g, nb1);
    }
    k_fin<<<BATCH, 64, 0, stream>>>(outsum_part, out);
}

// Round 21
// 243.516 us; speedup vs baseline: 2.2534x; 1.0101x over previous
//
#include <hip/hip_runtime.h>
#include <hip/hip_bf16.h>

#define SLOW 32
#define MSG 16
#define TSTEPS 4
#define BATCH 8
#define NI0 256
#define NO0 128
#define NI1 128
#define NO1 64

typedef __bf16 bf16x8 __attribute__((ext_vector_type(8)));
typedef float f32x4 __attribute__((ext_vector_type(4)));

__device__ __forceinline__ float rcpf(float x) { return __builtin_amdgcn_rcpf(x); }
__device__ __forceinline__ float sigf(float x) { return rcpf(1.f + __expf(-x)); }
__device__ __forceinline__ float tanh_apx(float x) {
    float xc = fminf(fmaxf(x, -15.f), 15.f);
    float e = __expf(-2.f * xc);
    return (1.f - e) * rcpf(1.f + e);
}
__device__ __forceinline__ unsigned short f2bf(float x) {
    __bf16 h = (__bf16)x;
    return __builtin_bit_cast(unsigned short, h);
}
__device__ __forceinline__ float bf2f(unsigned short u) {
    __bf16 h = __builtin_bit_cast(__bf16, u);
    return (float)h;
}
__device__ __forceinline__ float sum16(float v) {
    v += __shfl_xor(v, 1); v += __shfl_xor(v, 2);
    v += __shfl_xor(v, 4); v += __shfl_xor(v, 8);
    return v;
}

// ---------------------------------------------------------------------------
// k_prep: pack B-fragments (bf16) for Wh (8 nt), Wf, Wb, Wi-fwd (8 nt, K pad)
// ---------------------------------------------------------------------------
__global__ void k_prep(const float* __restrict__ Wh, const float* __restrict__ Wf,
                       const float* __restrict__ Wb, const float* __restrict__ Wi,
                       unsigned short* __restrict__ WhBp,
                       unsigned short* __restrict__ WfBp,
                       unsigned short* __restrict__ WbBp,
                       unsigned short* __restrict__ WiFp) {
    int i = blockIdx.x * 256 + threadIdx.x;
    if (i < 4096) {
        int e = i & 7, l = (i >> 3) & 63, nt = i >> 9;
        int k = (l >> 4) * 8 + e, col = nt * 16 + (l & 15);
        WhBp[i] = f2bf(Wh[k * 128 + col]);
    } else if (i < 4608) {
        int j = i - 4096;
        int e = j & 7, l = j >> 3;
        int k = (l >> 4) * 8 + e;
        WfBp[j] = f2bf(Wf[k * 16 + (l & 15)]);
    } else if (i < 5120) {
        int j = i - 4608;
        int e = j & 7, l = j >> 3;
        int k = (l >> 4) * 8 + e;
        WbBp[j] = f2bf(Wb[k * 16 + (l & 15)]);
    } else if (i < 9216) {
        int j = i - 5120;
        int e = j & 7, l = (j >> 3) & 63, nt = j >> 9;
        int k = (l >> 4) * 8 + e, col = nt * 16 + (l & 15);
        WiFp[j] = (k < 16) ? f2bf(Wi[k * 128 + col]) : (unsigned short)0;
    }
}

// ---------------------------------------------------------------------------
// Layer 0 (+ overlapped l1-merge & softmax riders).
// Wh B-fragments in registers; gate-base/wi0 values re-read from LDS at use
// (frees ~16 VGPRs toward the 85/73 occupancy steps; values identical).
// ---------------------------------------------------------------------------
__global__ __launch_bounds__(256) void k_l0(
    const float* __restrict__ inp, const float* __restrict__ Wi,
    const unsigned short* __restrict__ WhBp, const float* __restrict__ b_lstm,
    const unsigned short* __restrict__ WfBp, const float* __restrict__ bf_,
    const float* __restrict__ ln_fs, const float* __restrict__ ln_fb,
    unsigned short* __restrict__ h0bf, float* __restrict__ c0g,
    const unsigned short* __restrict__ hm0, const float* __restrict__ cm0,
    const unsigned int* __restrict__ h1bf, const float* __restrict__ c1g,
    unsigned short* __restrict__ hm1, float* __restrict__ cm1,
    const float* __restrict__ outsum_part, const int* __restrict__ labels,
    float* __restrict__ dout, float* __restrict__ gradP, float* __restrict__ ohP,
    const float* __restrict__ nb1, float* __restrict__ nf_part, int t) {
    int tid = threadIdx.x;
    if (blockIdx.x >= 2048) {
        int mb = blockIdx.x - 2048;
        if (mb < 256) {   // hm1
            int idx = mb * 256 + tid;
            int u = idx & 7, cell = (idx >> 3) & 127, no = idx >> 10;
            size_t base = ((size_t)no * 128 + cell) * 16 + u;
            const size_t strd = (size_t)NO1 * 128 * 16;
            float s0 = 0.f, s1 = 0.f;
#pragma unroll
            for (int b = 0; b < 8; b++) {
                unsigned int v = h1bf[base + b * strd];
                s0 += bf2f((unsigned short)(v & 0xffff));
                s1 += bf2f((unsigned short)(v >> 16));
            }
            ((unsigned int*)hm1)[((size_t)no * 128 + cell) * 8 + u] =
                (unsigned int)f2bf(s0 * 0.125f) | ((unsigned int)f2bf(s1 * 0.125f) << 16);
            return;
        }
        if (mb < 384) {   // cm1
            int idx = (mb - 256) * 256 + tid;
            int s4 = idx & 3, cell = (idx >> 2) & 127, no = idx >> 9;
            const float4* C = (const float4*)c1g;
            size_t base = ((size_t)no * 128 + cell) * 8 + s4;
            const size_t strd = (size_t)NO1 * 128 * 8;
            float4 a = {0.f, 0.f, 0.f, 0.f};
#pragma unroll
            for (int b = 0; b < 8; b++) {
                float4 v = C[base + b * strd];
                a.x += v.x; a.y += v.y; a.z += v.z; a.w += v.w;
            }
            a.x *= 0.125f; a.y *= 0.125f; a.z *= 0.125f; a.w *= 0.125f;
            ((float4*)cm1)[((size_t)no * 128 + cell) * 4 + s4] = a;
            return;
        }
        {   // softmax for step t-1
            int b = mb - 384;
            int no = tid;
            if (no < 64) {
                float v = (outsum_part[((size_t)b * NO1 + no) * 2] +
                           outsum_part[((size_t)b * NO1 + no) * 2 + 1]) * (1.f / 128.f);
                float mx = v;
#pragma unroll
                for (int d = 1; d < 64; d <<= 1) mx = fmaxf(mx, __shfl_xor(mx, d));
                float e = __expf(v - mx);
                float sum = e;
#pragma unroll
                for (int d = 1; d < 64; d <<= 1) sum += __shfl_xor(sum, d);
                int lbl = labels[(t - 1) * BATCH + b];
                float oh = (no == lbl) ? 1.f : 0.f;
                gradP[b * NO1 + no] = e / sum - oh;
                ohP[b * NO1 + no] = oh;
                dout[((size_t)(t - 1) * BATCH + b) * NO1 + no] = v;
            }
            return;
        }
    }

    int q = blockIdx.x & 1;
    int no = (blockIdx.x >> 1) & 127;
    int b = blockIdx.x >> 8;
    int w = __builtin_amdgcn_readfirstlane(tid >> 6);
    int l = tid & 63, lo = l & 15, hg = l >> 4;
    const bool wb = (t < TSTEPS - 1);

    __shared__ unsigned short Hbf[128 * 40];
    __shared__ float gsh[128];
    __shared__ float mi_l[128];
    __shared__ float wi0[128];
    __shared__ float redn[4][16];

    bf16x8 BWr[8];
#pragma unroll
    for (int nt = 0; nt < 8; nt++)
        BWr[nt] = *(const bf16x8*)&WhBp[(nt * 64 + l) * 8];

    if (tid < 128) {
        float acc = b_lstm[tid];
        if (t > 0) {
            const float* nbr = nb1 + ((size_t)b * NO0 + no) * MSG;
#pragma unroll
            for (int m = 0; m < MSG; m++) acc += nbr[m] * Wi[(MSG + m) * 128 + tid];
        }
        gsh[tid] = acc;
        wi0[tid] = Wi[tid];
        mi_l[tid] = inp[((size_t)t * BATCH + b) * NI0 + q * 128 + tid];
    }
    {
        int lc = tid >> 1, half = tid & 1;
        unsigned int* hl = (unsigned int*)Hbf;
        if (t > 0) {
            if (half == 0) {
                const unsigned int* hsrc = (const unsigned int*)hm0 +
                    ((size_t)no * 256 + q * 128 + lc) * 8;
#pragma unroll
                for (int j = 0; j < 8; j++) hl[lc * 20 + j] = hsrc[j];
            } else {
                const unsigned int* hsrc = (const unsigned int*)h0bf +
                    ((size_t)(b * NO0 + no) * 256 + q * 128 + lc) * 16 + 8;
#pragma unroll
                for (int j = 0; j < 8; j++) hl[lc * 20 + 8 + j] = hsrc[j];
            }
        } else {
#pragma unroll
            for (int j = 0; j < 8; j++) hl[lc * 20 + half * 8 + j] = 0u;
        }
    }
    size_t cbase = (size_t)(b * NO0 + no) * 256 * 32;
    float cst[2][4][2];
    if (t > 0) {
#pragma unroll
        for (int mi_ = 0; mi_ < 2; mi_++)
#pragma unroll
            for (int r = 0; r < 4; r++) {
                int gc = q * 128 + (w * 2 + mi_) * 16 + hg * 4 + r;
                cst[mi_][r][0] = cm0[((size_t)no * 256 + gc) * 16 + lo];
                cst[mi_][r][1] = c0g[cbase + (size_t)gc * 32 + lo + 16];
            }
    } else {
#pragma unroll
        for (int mi_ = 0; mi_ < 2; mi_++)
#pragma unroll
            for (int r = 0; r < 4; r++) { cst[mi_][r][0] = 0.f; cst[mi_][r][1] = 0.f; }
    }
    __syncthreads();

    f32x4 miv[2];
#pragma unroll
    for (int mi_ = 0; mi_ < 2; mi_++)
#pragma unroll
        for (int r = 0; r < 4; r++)
            miv[mi_][r] = mi_l[(w * 2 + mi_) * 16 + hg * 4 + r];

#pragma unroll
    for (int micro = 0; micro < 2; micro++) {
#pragma unroll
        for (int mi_ = 0; mi_ < 2; mi_++) {
            int lt = w * 2 + mi_;
            bf16x8 A = *(const bf16x8*)&Hbf[(lt * 16 + lo) * 40 + hg * 8];
            f32x4 acc[4];
#pragma unroll
            for (int g = 0; g < 4; g++) {
                int nt = 2 * g;
                // gate-base & wi0 re-read from LDS (broadcast) — saves VGPRs
                f32x4 ci = gsh[lo + 16 * nt] + miv[mi_] * wi0[lo + 16 * nt];
                acc[g] = __builtin_amdgcn_mfma_f32_16x16x32_bf16(A, BWr[nt], ci, 0, 0, 0);
            }
#pragma unroll
            for (int r = 0; r < 4; r++) {
                int lrow = lt * 16 + hg * 4 + r;
                float cn = sigf(acc[1][r]) * cst[mi_][r][0] + sigf(acc[0][r]) * tanh_apx(acc[2][r]);
                cst[mi_][r][0] = cn;
                float hv = sigf(acc[3][r]) * tanh_apx(cn);
                Hbf[lrow * 40 + lo] = f2bf(hv);
                if (micro == 1 && wb)
                    c0g[cbase + (size_t)(q * 128 + lrow) * 32 + lo] = cn;
            }
#pragma unroll
            for (int g = 0; g < 4; g++) {
                int nt = 2 * g + 1;
                f32x4 ci = gsh[lo + 16 * nt] + miv[mi_] * wi0[lo + 16 * nt];
                acc[g] = __builtin_amdgcn_mfma_f32_16x16x32_bf16(A, BWr[nt], ci, 0, 0, 0);
            }
#pragma unroll
            for (int r = 0; r < 4; r++) {
                int lrow = lt * 16 + hg * 4 + r;
                float cn = sigf(acc[1][r]) * cst[mi_][r][1] + sigf(acc[0][r]) * tanh_apx(acc[2][r]);
                cst[mi_][r][1] = cn;
                float hv = sigf(acc[3][r]) * tanh_apx(cn);
                Hbf[lrow * 40 + lo + 16] = f2bf(hv);
                if (micro == 1 && wb)
                    c0g[cbase + (size_t)(q * 128 + lrow) * 32 + lo + 16] = cn;
            }
        }
    }

    // epilogue: fm = LN(h @ Wf + bf)
    bf16x8 Ff = *(const bf16x8*)&WfBp[l * 8];
    float lnfs = ln_fs[lo], lnfb = ln_fb[lo];
    float bfv = bf_[lo];
    f32x4 cif = {bfv, bfv, bfv, bfv};
    float nfp = 0.f;
#pragma unroll
    for (int mi_ = 0; mi_ < 2; mi_++) {
        int lt = w * 2 + mi_;
        bf16x8 A = *(const bf16x8*)&Hbf[(lt * 16 + lo) * 40 + hg * 8];
        f32x4 f = __builtin_amdgcn_mfma_f32_16x16x32_bf16(A, Ff, cif, 0, 0, 0);
#pragma unroll
        for (int r = 0; r < 4; r++) {
            float x = f[r];
            float mean = sum16(x) * 0.0625f;
            float d = x - mean;
            float rs = rsqrtf(sum16(d * d) * 0.0625f + 1e-6f);
            nfp += d * rs * lnfs + lnfb;
        }
    }
    nfp += __shfl_xor(nfp, 16);
    nfp += __shfl_xor(nfp, 32);
    if (l < 16) redn[w][l] = nfp;
    __syncthreads();
    if (tid < 16)
        nf_part[(((size_t)b * NO0 + no) * 2 + q) * 16 + tid] =
            redn[0][tid] + redn[1][tid] + redn[2][tid] + redn[3][tid];

    if (wb) {
        int lc = tid >> 1, part = tid & 1;
        unsigned int* hdst =
            (unsigned int*)h0bf +
            ((size_t)(b * NO0 + no) * 256 + q * 128 + lc) * 16 + part * 8;
        const unsigned int* hl = (const unsigned int*)Hbf;
#pragma unroll
        for (int j = 0; j < 8; j++) hdst[j] = hl[lc * 20 + part * 8 + j];
    }
}

// ---------------------------------------------------------------------------
// Layer 1: blocks [0,1024) = LSTM; blocks [1024,2560) = layer-0 merge riders.
// ---------------------------------------------------------------------------
__global__ __launch_bounds__(256) void k_l1(
    const float* __restrict__ Wi, const unsigned short* __restrict__ WhBp,
    const float* __restrict__ b_lstm,
    const unsigned short* __restrict__ WfBp, const float* __restrict__ bf_,
    const float* __restrict__ ln_fs, const float* __restrict__ ln_fb,
    const unsigned short* __restrict__ WbBp, const float* __restrict__ bwb,
    const float* __restrict__ ln_bs, const float* __restrict__ ln_bb,
    const unsigned short* __restrict__ WiFp,
    unsigned short* __restrict__ h1bf, float* __restrict__ c1g,
    const unsigned short* __restrict__ hm1, const float* __restrict__ cm1,
    const unsigned short* __restrict__ h0bf, const float* __restrict__ c0g,
    unsigned short* __restrict__ hm0, float* __restrict__ cm0,
    const float* __restrict__ nf_part, const float* __restrict__ gradP,
    const float* __restrict__ ohP,
    float* __restrict__ bm_g, float* __restrict__ outsum_part, int t) {
    int tid = threadIdx.x;
    if (blockIdx.x >= 1024) {
        int mb = blockIdx.x - 1024;
        if (mb < 1024) {  // hm0
            int idx = mb * 256 + tid;
            int u = idx & 7, cell = (idx >> 3) & 255, no = idx >> 11;
            size_t base = ((size_t)no * 256 + cell) * 16 + u;
            const size_t strd = (size_t)NO0 * 256 * 16;
            const unsigned int* H = (const unsigned int*)h0bf;
            float s0 = 0.f, s1 = 0.f;
#pragma unroll
            for (int b = 0; b < 8; b++) {
                unsigned int v = H[base + b * strd];
                s0 += bf2f((unsigned short)(v & 0xffff));
                s1 += bf2f((unsigned short)(v >> 16));
            }
            ((unsigned int*)hm0)[((size_t)no * 256 + cell) * 8 + u] =
                (unsigned int)f2bf(s0 * 0.125f) | ((unsigned int)f2bf(s1 * 0.125f) << 16);
        } else {          // cm0
            int idx = (mb - 1024) * 256 + tid;
            int s4 = idx & 3, cell = (idx >> 2) & 255, no = idx >> 10;
            const float4* C = (const float4*)c0g;
            size_t base = ((size_t)no * 256 + cell) * 8 + s4;
            const size_t strd = (size_t)NO0 * 256 * 8;
            float4 a = {0.f, 0.f, 0.f, 0.f};
#pragma unroll
            for (int b = 0; b < 8; b++) {
                float4 v = C[base + b * strd];
                a.x += v.x; a.y += v.y; a.z += v.z; a.w += v.w;
            }
            a.x *= 0.125f; a.y *= 0.125f; a.z *= 0.125f; a.w *= 0.125f;
            ((float4*)cm0)[((size_t)no * 256 + cell) * 4 + s4] = a;
        }
        return;
    }

    int q = blockIdx.x & 1;
    int no = (blockIdx.x >> 1) & 63;
    int b = blockIdx.x >> 7;
    int w = __builtin_amdgcn_readfirstlane(tid >> 6);
    int l = tid & 63, lo = l & 15, hg = l >> 4;
    const bool wb = (t < TSTEPS - 1);

    __shared__ unsigned short Hbf[64 * 40];
    __shared__ float gsh[128];
    __shared__ float red[4];

    bf16x8 BWr[8];
#pragma unroll
    for (int nt = 0; nt < 8; nt++)
        BWr[nt] = *(const bf16x8*)&WhBp[(nt * 64 + l) * 8];

    if (tid < 128) {
        float acc = b_lstm[tid];
        if (t > 0) {
            float g = gradP[b * NO1 + no], oh = ohP[b * NO1 + no];
            acc += g * Wi[MSG * 128 + tid] + oh * Wi[(MSG + 1) * 128 + tid];
        }
        gsh[tid] = acc;
    }
    {
        int lc = tid >> 2, part = tid & 3;
        unsigned int* hl = (unsigned int*)Hbf;
        if (t > 0) {
            if (part < 2) {
                const unsigned int* hsrc = (const unsigned int*)hm1 +
                    ((size_t)no * 128 + q * 64 + lc) * 8 + part * 4;
#pragma unroll
                for (int j = 0; j < 4; j++) hl[lc * 20 + part * 4 + j] = hsrc[j];
            } else {
                const unsigned int* hsrc = (const unsigned int*)h1bf +
                    ((size_t)(b * NO1 + no) * 128 + q * 64 + lc) * 16 + part * 4;
#pragma unroll
                for (int j = 0; j < 4; j++) hl[lc * 20 + part * 4 + j] = hsrc[j];
            }
        } else {
#pragma unroll
            for (int j = 0; j < 4; j++) hl[lc * 20 + part * 4 + j] = 0u;
        }
    }
    size_t cbase = (size_t)(b * NO1 + no) * 128 * 32;
    float cst[4][2];
    if (t > 0) {
#pragma unroll
        for (int r = 0; r < 4; r++) {
            int gc = q * 64 + w * 16 + hg * 4 + r;
            cst[r][0] = cm1[((size_t)no * 128 + gc) * 16 + lo];
            cst[r][1] = c1g[cbase + (size_t)gc * 32 + lo + 16];
        }
    } else {
#pragma unroll
        for (int r = 0; r < 4; r++) { cst[r][0] = 0.f; cst[r][1] = 0.f; }
    }
    bf16x8 Anf;
#pragma unroll
    for (int e = 0; e < 8; e++) Anf[e] = (__bf16)0.f;
    if (hg < 2) {
        const float* p = nf_part +
            ((size_t)b * 128 + q * 64 + w * 16 + lo) * 32 + hg * 8;
#pragma unroll
        for (int e = 0; e < 8; e++)
            Anf[e] = (__bf16)((p[e] + p[e + 16]) * (1.f / 256.f));
    }
    __syncthreads();

    f32x4 xf4[8];
    {
        f32x4 zz = {0.f, 0.f, 0.f, 0.f};
#pragma unroll
        for (int nt = 0; nt < 8; nt++) {
            bf16x8 B = *(const bf16x8*)&WiFp[(nt * 64 + l) * 8];
            xf4[nt] = __builtin_amdgcn_mfma_f32_16x16x32_bf16(Anf, B, zz, 0, 0, 0);
        }
    }

#pragma unroll
    for (int micro = 0; micro < 2; micro++) {
        bf16x8 A = *(const bf16x8*)&Hbf[(w * 16 + lo) * 40 + hg * 8];
        f32x4 acc[4];
#pragma unroll
        for (int g = 0; g < 4; g++) {
            int nt = 2 * g;
            f32x4 ci = xf4[nt] + gsh[lo + 16 * nt];
            acc[g] = __builtin_amdgcn_mfma_f32_16x16x32_bf16(A, BWr[nt], ci, 0, 0, 0);
        }
#pragma unroll
        for (int r = 0; r < 4; r++) {
            float cn = sigf(acc[1][r]) * cst[r][0] + sigf(acc[0][r]) * tanh_apx(acc[2][r]);
            cst[r][0] = cn;
            float hv = sigf(acc[3][r]) * tanh_apx(cn);
            Hbf[(w * 16 + hg * 4 + r) * 40 + lo] = f2bf(hv);
            if (micro == 1 && wb)
                c1g[cbase + (size_t)(q * 64 + w * 16 + hg * 4 + r) * 32 + lo] = cn;
        }
#pragma unroll
        for (int g = 0; g < 4; g++) {
            int nt = 2 * g + 1;
            f32x4 ci = xf4[nt] + gsh[lo + 16 * nt];
            acc[g] = __builtin_amdgcn_mfma_f32_16x16x32_bf16(A, BWr[nt], ci, 0, 0, 0);
        }
#pragma unroll
        for (int r = 0; r < 4; r++) {
            float cn = sigf(acc[1][r]) * cst[r][1] + sigf(acc[0][r]) * tanh_apx(acc[2][r]);
            cst[r][1] = cn;
            float hv = sigf(acc[3][r]) * tanh_apx(cn);
            Hbf[(w * 16 + hg * 4 + r) * 40 + lo + 16] = f2bf(hv);
            if (micro == 1 && wb)
                c1g[cbase + (size_t)(q * 64 + w * 16 + hg * 4 + r) * 32 + lo + 16] = cn;
        }
    }

    bf16x8 Ff = *(const bf16x8*)&WfBp[l * 8];
    float lnfs = ln_fs[lo], lnfb = ln_fb[lo];
    float bfv = bf_[lo];
    f32x4 cif = {bfv, bfv, bfv, bfv};
    float op = 0.f;
    {
        bf16x8 A = *(const bf16x8*)&Hbf[(w * 16 + lo) * 40 + hg * 8];
        f32x4 f = __builtin_amdgcn_mfma_f32_16x16x32_bf16(A, Ff, cif, 0, 0, 0);
#pragma unroll
        for (int r = 0; r < 4; r++) {
            float x = f[r];
            float mean = sum16(x) * 0.0625f;
            float d = x - mean;
            float rs = rsqrtf(sum16(d * d) * 0.0625f + 1e-6f);
            op += d * rs * lnfs + lnfb;
        }
        if (wb) {
            bf16x8 Bb = *(const bf16x8*)&WbBp[l * 8];
            float lnbs = ln_bs[lo], lnbb = ln_bb[lo];
            float bwv = bwb[lo];
            f32x4 cib = {bwv, bwv, bwv, bwv};
            f32x4 g = __builtin_amdgcn_mfma_f32_16x16x32_bf16(A, Bb, cib, 0, 0, 0);
#pragma unroll
            for (int r = 0; r < 4; r++) {
                int gc = q * 64 + w * 16 + hg * 4 + r;
                float x = g[r];
                float mean = sum16(x) * 0.0625f;
                float d = x - mean;
                float rs = rsqrtf(sum16(d * d) * 0.0625f + 1e-6f);
                bm_g[(((size_t)b * NO1 + no) * MSG + lo) * NI1 + gc] = d * rs * lnbs + lnbb;
            }
        }
    }
    op += __shfl_xor(op, 16);
    op += __shfl_xor(op, 32);
    if (l == 0) red[w] = op;
    __syncthreads();
    if (tid == 0)
        outsum_part[((size_t)b * NO1 + no) * 2 + q] = red[0] + red[1] + red[2] + red[3];

    if (wb) {
        int lc = tid >> 2, part = tid & 3;
        unsigned int* hdst =
            (unsigned int*)h1bf +
            ((size_t)(b * NO1 + no) * 128 + q * 64 + lc) * 16 + part * 4;
        const unsigned int* hl = (const unsigned int*)Hbf;
#pragma unroll
        for (int j = 0; j < 4; j++) hdst[j] = hl[lc * 20 + part * 4 + j];
    }
}

// ---------------------------------------------------------------------------
// k_nb (t < TSTEPS-1): nb1[b][ni][m] = mean over no1 of bm_g
// ---------------------------------------------------------------------------
__global__ __launch_bounds__(256) void k_nb(const float* __restrict__ bm_g,
                                            float* __restrict__ nb1) {
    int g = blockIdx.x * 256 + threadIdx.x;  // < 16384
    int ni = g & 127;
    int m = (g >> 7) & 15;
    int b = g >> 11;
    float a = 0.f;
#pragma unroll 8
    for (int no = 0; no < NO1; no++)
        a += bm_g[(((size_t)b * NO1 + no) * MSG + m) * NI1 + ni];
    nb1[((size_t)b * NI1 + ni) * MSG + m] = a * (1.f / NO1);
}

// ---------------------------------------------------------------------------
// k_fin: final-step dout
// ---------------------------------------------------------------------------
__global__ void k_fin(const float* __restrict__ outsum_part,
                      float* __restrict__ dout) {
    int b = blockIdx.x;
    int no = threadIdx.x;
    float v = (outsum_part[((size_t)b * NO1 + no) * 2] +
               outsum_part[((size_t)b * NO1 + no) * 2 + 1]) * (1.f / 128.f);
    dout[((size_t)(TSTEPS - 1) * BATCH + b) * NO1 + no] = v;
}

// ---------------------------------------------------------------------------

extern "C" void kernel_launch(void* const* d_in, const int* in_sizes, int n_in,
                              void* d_out, int out_size, void* d_ws, size_t ws_size,
                              hipStream_t stream) {
    const float* inp   = (const float*)d_in[0];
    const int*   labels= (const int*)d_in[1];
    const float* Wi    = (const float*)d_in[2];
    const float* Wh    = (const float*)d_in[3];
    const float* b_lstm= (const float*)d_in[4];
    const float* Wf    = (const float*)d_in[5];
    const float* bf_   = (const float*)d_in[6];
    const float* Wb    = (const float*)d_in[7];
    const float* bwb   = (const float*)d_in[8];
    const float* ln_fs = (const float*)d_in[9];
    const float* ln_fb = (const float*)d_in[10];
    const float* ln_bs = (const float*)d_in[11];
    const float* ln_bb = (const float*)d_in[12];
    float* out = (float*)d_out;

    const size_t SZ0 = (size_t)BATCH * NO0 * 256 * 32;  // 8,388,608
    const size_t SZ1 = (size_t)BATCH * NO1 * 128 * 32;  // 2,097,152

    float* c0 = (float*)d_ws;
    float* c1 = c0 + SZ0;
    unsigned short* h0bf = (unsigned short*)(c1 + SZ1);
    unsigned short* h1bf = h0bf + SZ0;
    float* cm0         = (float*)(h1bf + SZ1);          // 524,288 f
    float* cm1         = cm0 + 524288;                  // 131,072 f
    unsigned short* hm0 = (unsigned short*)(cm1 + 131072);  // 524,288 us
    unsigned short* hm1 = hm0 + 524288;                 // 131,072 us
    float* bm_g        = (float*)(hm1 + 131072);        // 1,048,576 f
    float* nf_part     = bm_g + 1048576;                // 32,768 f
    float* nb1         = nf_part + 32768;               // 16,384 f
    float* outsum_part = nb1 + 16384;                   // 1,024 f
    float* gradP       = outsum_part + 1024;            // 512
    float* ohP         = gradP + 512;                   // 512
    unsigned short* WhBp = (unsigned short*)(ohP + 512);
    unsigned short* WfBp = WhBp + 4096;
    unsigned short* WbBp = WfBp + 512;
    unsigned short* WiFp = WbBp + 512;                  // 4096

    k_prep<<<36, 256, 0, stream>>>(Wh, Wf, Wb, Wi, WhBp, WfBp, WbBp, WiFp);

    for (int t = 0; t < TSTEPS; t++) {
        int l0grid = (t > 0) ? 2440 : 2048;
        k_l0<<<l0grid, 256, 0, stream>>>(inp, Wi, WhBp, b_lstm, WfBp, bf_,
                                         ln_fs, ln_fb, h0bf, c0, hm0, cm0,
                                         (const unsigned int*)h1bf, c1, hm1, cm1,
                                         outsum_part, labels, out, gradP, ohP,
                                         nb1, nf_part, t);
        int l1grid = (t < TSTEPS - 1) ? 2560 : 1024;
        k_l1<<<l1grid, 256, 0, stream>>>(Wi, WhBp, b_lstm, WfBp, bf_,
                                         ln_fs, ln_fb, WbBp, bwb, ln_bs, ln_bb,
                                         WiFp, h1bf, c1, hm1, cm1,
                                         h0bf, c0, hm0, cm0,
                                         nf_part, gradP, ohP,
                                         bm_g, outsum_part, t);
        if (t < TSTEPS - 1)
            k_nb<<<64, 256, 0, stream>>>(bm_g, nb1);
    }
    k_fin<<<BATCH, 64, 0, stream>>>(outsum_part, out);
}